// Round 9
// baseline (3770.159 us; speedup 1.0000x reference)
//
#include <hip/hip_runtime.h>

#define N_NODES 10000
#define N_EDGES 160000
#define CIN 64
#define COUT 128
#define KTOT 125
#define NBINS (N_NODES * KTOT)          // 1,250,000
#define NPAIRS (N_EDGES * 8)            // 1,280,000
#define EPS 1e-5f

#define CDIV(a,b) (((a)+(b)-1)/(b))

typedef __attribute__((ext_vector_type(8))) short short8;
typedef __attribute__((ext_vector_type(4))) float floatx4;

static __device__ __forceinline__ unsigned short f2b(float f) {
  union { float f; unsigned u; } v; v.f = f;
  unsigned r = v.u + 0x7FFFu + ((v.u >> 16) & 1u);
  return (unsigned short)(r >> 16);
}
static __device__ __forceinline__ float b2f(unsigned short u) {
  union { unsigned u; float f; } v; v.u = ((unsigned)u) << 16;
  return v.f;
}

// ---------------- edge CSR (dst-sorted edge order for write locality) ----------
__global__ void ecount(const int* __restrict__ dst, int* __restrict__ ecnt, int E) {
  int e = blockIdx.x * 256 + threadIdx.x;
  if (e < E) atomicAdd(&ecnt[dst[e]], 1);
}

// single-block exclusive scan over n=10000; also seeds ecur with the prefix
__global__ void escan(const int* __restrict__ cnt, int* __restrict__ rowptr,
                      int* __restrict__ cur, int n) {
  __shared__ int buf[256];
  __shared__ int carry;
  if (threadIdx.x == 0) { carry = 0; rowptr[0] = 0; }
  __syncthreads();
  for (int base = 0; base < n; base += 256) {
    int i = base + threadIdx.x;
    int v = (i < n) ? cnt[i] : 0;
    buf[threadIdx.x] = v;
    __syncthreads();
    for (int s = 1; s < 256; s <<= 1) {
      int t = (threadIdx.x >= s) ? buf[threadIdx.x - s] : 0;
      __syncthreads();
      buf[threadIdx.x] += t;
      __syncthreads();
    }
    if (i < n) {
      int incl = carry + buf[threadIdx.x];
      rowptr[i + 1] = incl;
      cur[i] = incl - v;
    }
    __syncthreads();
    if (threadIdx.x == 255) carry += buf[255];
    __syncthreads();
  }
}

__global__ void efill(const int* __restrict__ dst, int* __restrict__ ecur,
                      int* __restrict__ eorder, int E) {
  int e = blockIdx.x * 256 + threadIdx.x;
  if (e >= E) return;
  int pos = atomicAdd(&ecur[dst[e]], 1);
  eorder[pos] = e;
}

// ---------------- (dst,k)-pair counting sort ----------------
static __device__ __forceinline__ void spline_corners(const float* __restrict__ attr, int e,
                                                      float* w8, int* k8) {
  float v0 = attr[e * 3 + 0] * 4.f;
  float v1 = attr[e * 3 + 1] * 4.f;
  float v2 = attr[e * 3 + 2] * 4.f;
  float b0 = floorf(v0), b1 = floorf(v1), b2 = floorf(v2);
  float f0 = v0 - b0, f1 = v1 - b1, f2 = v2 - b2;
  int i0 = (int)b0, i1 = (int)b1, i2 = (int)b2;
#pragma unroll
  for (int combo = 0; combo < 8; combo++) {
    int bit0 = combo & 1, bit1 = (combo >> 1) & 1, bit2 = (combo >> 2) & 1;
    w8[combo] = (bit0 ? f0 : 1.f - f0) * (bit1 ? f1 : 1.f - f1) * (bit2 ? f2 : 1.f - f2);
    int k0 = min(max(i0 + bit0, 0), 4);
    int k1 = min(max(i1 + bit1, 0), 4);
    int k2 = min(max(i2 + bit2, 0), 4);
    k8[combo] = k0 * 25 + k1 * 5 + k2;
  }
}

// iterate edges in dst-sorted order -> cnt2 atomics localized
__global__ void pair_count(const int* __restrict__ eorder, const int* __restrict__ dst,
                           const float* __restrict__ attr, int* __restrict__ cnt2, int E) {
  int i = blockIdx.x * 256 + threadIdx.x;
  if (i >= E) return;
  int e = eorder[i];
  int d = dst[e];
  float w8[8]; int k8[8];
  spline_corners(attr, e, w8, k8);
#pragma unroll
  for (int c = 0; c < 8; c++) atomicAdd(&cnt2[d * KTOT + k8[c]], 1);
}

// weights pre-divided by deg(dst): spline GEMM then directly yields the mean
// aggregation, so the root GEMM can share the same accumulator (no deg at finalize).
__global__ void pair_fill(const int* __restrict__ eorder, const int* __restrict__ src,
                          const int* __restrict__ dst, const float* __restrict__ attr,
                          const int* __restrict__ erowptr,
                          int* __restrict__ cur2, int2* __restrict__ pairs, int E) {
  int i = blockIdx.x * 256 + threadIdx.x;
  if (i >= E) return;
  int e = eorder[i];
  int s = src[e], d = dst[e];
  float invdeg = 1.0f / fmaxf((float)(erowptr[d + 1] - erowptr[d]), 1.0f);
  float w8[8]; int k8[8];
  spline_corners(attr, e, w8, k8);
#pragma unroll
  for (int c = 0; c < 8; c++) {
    int b = d * KTOT + k8[c];
    int pos = atomicAdd(&cur2[b], 1);
    int2 rec; rec.x = s; rec.y = __float_as_int(w8[c] * invdeg);
    pairs[pos] = rec;
  }
}

// ---------------- 3-kernel exclusive scan over NBINS ints ----------------
__global__ void scan_a(const int* __restrict__ in, int* __restrict__ bsum, int n) {
  __shared__ int red[256];
  int base = blockIdx.x * 2048 + threadIdx.x * 8;
  int s = 0;
#pragma unroll
  for (int j = 0; j < 8; j++) { int i = base + j; if (i < n) s += in[i]; }
  red[threadIdx.x] = s;
  __syncthreads();
  for (int st = 128; st > 0; st >>= 1) {
    if (threadIdx.x < st) red[threadIdx.x] += red[threadIdx.x + st];
    __syncthreads();
  }
  if (threadIdx.x == 0) bsum[blockIdx.x] = red[0];
}

// also zeroes the stats block (piggyback; must run before any finalize kernel)
__global__ void scan_b(const int* __restrict__ bsum, int* __restrict__ boff, int nb,
                       int* __restrict__ rowptr2, int nbins, float* __restrict__ stats) {
  for (int i = threadIdx.x; i < 6 * 128; i += 256) stats[i] = 0.f;
  __shared__ int buf[256];
  __shared__ int carry;
  if (threadIdx.x == 0) carry = 0;
  __syncthreads();
  for (int base = 0; base < nb; base += 256) {
    int i = base + threadIdx.x;
    int v = (i < nb) ? bsum[i] : 0;
    buf[threadIdx.x] = v;
    __syncthreads();
    for (int s = 1; s < 256; s <<= 1) {
      int t = (threadIdx.x >= s) ? buf[threadIdx.x - s] : 0;
      __syncthreads();
      buf[threadIdx.x] += t;
      __syncthreads();
    }
    if (i < nb) boff[i] = carry + buf[threadIdx.x] - v;
    __syncthreads();
    if (threadIdx.x == 255) carry += buf[255];
    __syncthreads();
  }
  if (threadIdx.x == 0) rowptr2[nbins] = carry;
}

// writes rowptr2[i] and seeds cur2[i] with the same value
__global__ void scan_c(const int* __restrict__ in, const int* __restrict__ boff,
                       int* __restrict__ rowptr2, int* __restrict__ cur2, int n) {
  __shared__ int buf[256];
  int base = blockIdx.x * 2048 + threadIdx.x * 8;
  int v[8], p[8];
  int s = 0;
#pragma unroll
  for (int j = 0; j < 8; j++) {
    int i = base + j;
    v[j] = (i < n) ? in[i] : 0;
    p[j] = s;
    s += v[j];
  }
  buf[threadIdx.x] = s;
  __syncthreads();
  for (int st = 1; st < 256; st <<= 1) {
    int t = (threadIdx.x >= st) ? buf[threadIdx.x - st] : 0;
    __syncthreads();
    buf[threadIdx.x] += t;
    __syncthreads();
  }
  int thr_excl = buf[threadIdx.x] - s;
  int b0 = boff[blockIdx.x];
#pragma unroll
  for (int j = 0; j < 8; j++) {
    int i = base + j;
    if (i < n) { int val = b0 + thr_excl + p[j]; rowptr2[i] = val; cur2[i] = val; }
  }
}

// ---------------- one-shot convert: xb + all weight transposes ----------------
__global__ void convert_all(const float* __restrict__ x, const float* __restrict__ W1,
                            const float* __restrict__ W2, const float* __restrict__ Wr1,
                            const float* __restrict__ Wrsc, const float* __restrict__ Wr2,
                            const float* __restrict__ Wsc,
                            unsigned short* __restrict__ xb, unsigned short* __restrict__ W1aug,
                            unsigned short* __restrict__ W2t, unsigned short* __restrict__ rootBt,
                            unsigned short* __restrict__ Wr2t) {
  long i = (long)blockIdx.x * 256 + threadIdx.x;
  const long n0 = 640000, n1 = n0 + 1024000, n2 = n1 + 2048000,
             n3 = n2 + 8192, n4 = n3 + 8192, n5 = n4 + 16384, n6 = n5 + 1024000;
  if (i < n0) {
    xb[i] = f2b(x[i]);
  } else if (i < n1) {
    long j = i - n0; int k = (int)(j >> 7), c = (int)(j & 127);
    W1aug[(long)c * 8000 + k] = f2b(W1[j]);
  } else if (i < n2) {
    long j = i - n1; int k = (int)(j >> 7), c = (int)(j & 127);
    W2t[(long)c * 16000 + k] = f2b(W2[j]);
  } else if (i < n3) {
    long j = i - n2; int k = (int)(j >> 7), c = (int)(j & 127);
    rootBt[c * 64 + k] = f2b(Wr1[j]);
  } else if (i < n4) {
    long j = i - n3; int k = (int)(j >> 7), c = (int)(j & 127);
    rootBt[(128 + c) * 64 + k] = f2b(Wrsc[j]);
  } else if (i < n5) {
    long j = i - n4; int k = (int)(j >> 7), c = (int)(j & 127);
    Wr2t[c * 128 + k] = f2b(Wr2[j]);
  } else if (i < n6) {
    long j = i - n5;
    int c = (int)(j / 8000), kk = (int)(j % 8000);
    W1aug[(long)(128 + c) * 8000 + kk] = f2b(Wsc[(kk & 63) * 128 + c]);
  }
}

// ---------------- fused scatter+GEMM (+root as extra K-step) ----------------
// Block: 128 rows x NC cols. Per spline k-bin: gather acc tile into LDS (no HBM
// acc round-trip), MFMA accumulate. Slice z==last also folds the root GEMM
// (As = Xb rows). Weights carry 1/deg, so the output is mean-aggregated + root.
template<int CK, int NC>
__global__ __launch_bounds__(256, 2) void fused_conv(
    const unsigned short* __restrict__ Xb, const int* __restrict__ rowptr2,
    const int2* __restrict__ pairs, const unsigned short* __restrict__ Wt,
    const unsigned short* __restrict__ rootW, float* __restrict__ C,
    int M, int kb0, int kbn, int do_root) {
  constexpr int LDA = CK + 8;            // pad: conflict-free MFMA ds_reads
  constexpr int NT = NC / 16;            // col tiles per wave-row
  __shared__ unsigned short As[128 * LDA];
  __shared__ unsigned short Bs[NC * LDA];
  int w = threadIdx.x >> 6, lane = threadIdx.x & 63;
  int row0 = blockIdx.x * 128;
  int q = lane >> 4, m16 = lane & 15;

  floatx4 acc[2][NT];
#pragma unroll
  for (int t = 0; t < 2; t++)
#pragma unroll
    for (int ct = 0; ct < NT; ct++) acc[t][ct] = (floatx4){0.f, 0.f, 0.f, 0.f};

  int nsteps = kbn + (do_root ? 1 : 0);
  for (int s = 0; s < nsteps; s++) {
    bool root = (s == kbn);
    int k = kb0 + s;
    __syncthreads();
    // ---- fill As (128 x CK) ----
    if (!root) {
      int j = lane & 31;
      int r = row0 + w * 32 + j;
      int pA = 0, pB = 0;
      if (r < M) {
        long bb = (long)r * KTOT + k;
        pA = rowptr2[bb]; pB = rowptr2[bb + 1];
      }
#pragma unroll 4
      for (int j2 = 0; j2 < 32; j2++) {
        int p0 = __shfl(pA, j2, 64);
        int p1 = __shfl(pB, j2, 64);
        if (CK == 64) {
          float a = 0.f;
          for (int p = p0; p < p1; p++) {
            int2 rec = pairs[p];
            a += __int_as_float(rec.y) * b2f(Xb[(long)rec.x * 64 + lane]);
          }
          As[(w * 32 + j2) * LDA + lane] = f2b(a);
        } else {
          float a0 = 0.f, a1 = 0.f;
          for (int p = p0; p < p1; p++) {
            int2 rec = pairs[p];
            float wv = __int_as_float(rec.y);
            unsigned u = *(const unsigned*)(Xb + (long)rec.x * 128 + lane * 2);
            a0 += wv * b2f((unsigned short)(u & 0xffffu));
            a1 += wv * b2f((unsigned short)(u >> 16));
          }
          unsigned pk = (unsigned)f2b(a0) | ((unsigned)f2b(a1) << 16);
          *(unsigned*)(As + (w * 32 + j2) * LDA + lane * 2) = pk;
        }
      }
    } else {
      constexpr int RPL = 1024 / (CK * 2);   // rows per wave-load: 8 or 4
      constexpr int LPR = 64 / RPL;          // lanes per row
#pragma unroll
      for (int it = 0; it < 32 / RPL; it++) {
        int rl = w * 32 + it * RPL + lane / LPR;
        int rg = row0 + rl; if (rg >= M) rg = M - 1;
        int cofs = (lane % LPR) * 8;
        short8 v = *(const short8*)(Xb + (long)rg * CK + cofs);
        *(short8*)(As + rl * LDA + cofs) = v;
      }
    }
    // ---- fill Bs (NC x CK) ----
    {
      const unsigned short* bsrc = root ? rootW : Wt;
      long bstride = root ? CK : (long)KTOT * CK;
      long koff = root ? 0 : (long)k * CK;
      constexpr int RPL = 1024 / (CK * 2);
      constexpr int LPR = 64 / RPL;
      constexpr int RPW = NC / 4;            // rows per wave
#pragma unroll
      for (int it = 0; it < RPW / RPL; it++) {
        int c = w * RPW + it * RPL + lane / LPR;
        int cofs = (lane % LPR) * 8;
        short8 v = *(const short8*)(bsrc + (long)c * bstride + koff + cofs);
        *(short8*)(Bs + c * LDA + cofs) = v;
      }
    }
    __syncthreads();
    // ---- MFMA ----
#pragma unroll
    for (int kk = 0; kk < CK / 32; kk++) {
      short8 a0 = *(const short8*)(As + (w * 32 + m16) * LDA + kk * 32 + q * 8);
      short8 a1 = *(const short8*)(As + (w * 32 + 16 + m16) * LDA + kk * 32 + q * 8);
#pragma unroll
      for (int ct = 0; ct < NT; ct++) {
        short8 b = *(const short8*)(Bs + (ct * 16 + m16) * LDA + kk * 32 + q * 8);
        acc[0][ct] = __builtin_amdgcn_mfma_f32_16x16x32_bf16(a0, b, acc[0][ct], 0, 0, 0);
        acc[1][ct] = __builtin_amdgcn_mfma_f32_16x16x32_bf16(a1, b, acc[1][ct], 0, 0, 0);
      }
    }
  }
  // ---- epilogue: atomic accumulate ----
#pragma unroll
  for (int t = 0; t < 2; t++) {
#pragma unroll
    for (int ct = 0; ct < NT; ct++) {
#pragma unroll
      for (int r = 0; r < 4; r++) {
        int orow = row0 + w * 32 + t * 16 + q * 4 + r;
        if (orow < M) atomicAdd(&C[(long)orow * NC + ct * 16 + m16], acc[t][ct][r]);
      }
    }
  }
}

// ---------------- epilogues ----------------
__global__ void finalize_stats(const float* __restrict__ msgaug,
                               const float* __restrict__ bias,
                               float* __restrict__ out, float* __restrict__ stats, int n) {
  int c = threadIdx.x & 127;
  float bv = bias[c];
  float s = 0.f, s2 = 0.f;
  long tot = (long)n * COUT;
  long stride = (long)gridDim.x * 256;
  for (long i = (long)blockIdx.x * 256 + threadIdx.x; i < tot; i += stride) {
    int r = (int)(i >> 7);
    float v = msgaug[(long)r * 256 + c] + bv;
    out[i] = v;
    s += v; s2 += v * v;
  }
  __shared__ float ls[256], ls2[256];
  ls[threadIdx.x] = s; ls2[threadIdx.x] = s2;
  __syncthreads();
  if (threadIdx.x < 128) {
    atomicAdd(&stats[c], ls[threadIdx.x] + ls[threadIdx.x + 128]);
    atomicAdd(&stats[128 + c], ls2[threadIdx.x] + ls2[threadIdx.x + 128]);
  }
}

__global__ void finalize2_dual(const float* __restrict__ msg2, const float* __restrict__ b2,
                               const float* __restrict__ msgaug, const float* __restrict__ bsc,
                               float* __restrict__ h2r, float* __restrict__ sraw,
                               float* __restrict__ stats2, float* __restrict__ statssc, int n) {
  int c = threadIdx.x & 127;
  float bv2 = b2[c], bvsc = bsc[c];
  float sa = 0.f, sb = 0.f, ta = 0.f, tb = 0.f;
  long tot = (long)n * COUT;
  long stride = (long)gridDim.x * 256;
  for (long i = (long)blockIdx.x * 256 + threadIdx.x; i < tot; i += stride) {
    int r = (int)(i >> 7);
    float v2 = msg2[i] + bv2;
    h2r[i] = v2;
    sa += v2; sb += v2 * v2;
    float vs = msgaug[(long)r * 256 + 128 + c] + bvsc;
    sraw[i] = vs;
    ta += vs; tb += vs * vs;
  }
  __shared__ float l0[256], l1[256], l2[256], l3[256];
  l0[threadIdx.x] = sa; l1[threadIdx.x] = sb; l2[threadIdx.x] = ta; l3[threadIdx.x] = tb;
  __syncthreads();
  if (threadIdx.x < 128) {
    atomicAdd(&stats2[c], l0[threadIdx.x] + l0[threadIdx.x + 128]);
    atomicAdd(&stats2[128 + c], l1[threadIdx.x] + l1[threadIdx.x + 128]);
    atomicAdd(&statssc[c], l2[threadIdx.x] + l2[threadIdx.x + 128]);
    atomicAdd(&statssc[128 + c], l3[threadIdx.x] + l3[threadIdx.x + 128]);
  }
}

__global__ void bn_elu_kernel(float* __restrict__ h, unsigned short* __restrict__ hb,
                              const float* __restrict__ stats, const float* __restrict__ g,
                              const float* __restrict__ be, int n) {
  long i = (long)blockIdx.x * 256 + threadIdx.x;
  if (i >= (long)n * COUT) return;
  int c = (int)(i & 127);
  float inv_n = 1.0f / n;
  float mu = stats[c] * inv_n;
  float var = stats[128 + c] * inv_n - mu * mu;
  float v = (h[i] - mu) * rsqrtf(var + EPS) * g[c] + be[c];
  v = v > 0.f ? v : expm1f(v);
  h[i] = v;
  hb[i] = f2b(v);
}

__global__ void final_out_kernel(const float* __restrict__ h2, const float* __restrict__ sraw,
                                 const float* __restrict__ st2, const float* __restrict__ stsc,
                                 const float* __restrict__ g2, const float* __restrict__ be2,
                                 const float* __restrict__ gsc, const float* __restrict__ besc,
                                 float* __restrict__ out, int n) {
  long i = (long)blockIdx.x * 256 + threadIdx.x;
  if (i >= (long)n * COUT) return;
  int c = (int)(i & 127);
  float inv_n = 1.0f / n;
  float mu2 = st2[c] * inv_n;
  float var2 = st2[128 + c] * inv_n - mu2 * mu2;
  float a = (h2[i] - mu2) * rsqrtf(var2 + EPS) * g2[c] + be2[c];
  float musc = stsc[c] * inv_n;
  float varsc = stsc[128 + c] * inv_n - musc * musc;
  float b = (sraw[i] - musc) * rsqrtf(varsc + EPS) * gsc[c] + besc[c];
  float v = a + b;
  out[i] = v > 0.f ? v : expm1f(v);
}

// ---------------- host ----------------
extern "C" void kernel_launch(void* const* d_in, const int* in_sizes, int n_in,
                              void* d_out, int out_size, void* d_ws, size_t ws_size,
                              hipStream_t stream) {
  const float* x    = (const float*)d_in[0];
  const int*   eidx = (const int*)d_in[1];
  const float* attr = (const float*)d_in[2];
  const float* W1   = (const float*)d_in[3];
  const float* Wr1  = (const float*)d_in[4];
  const float* b1   = (const float*)d_in[5];
  const float* g1   = (const float*)d_in[6];
  const float* be1  = (const float*)d_in[7];
  const float* W2   = (const float*)d_in[8];
  const float* Wr2  = (const float*)d_in[9];
  const float* b2   = (const float*)d_in[10];
  const float* g2   = (const float*)d_in[11];
  const float* be2  = (const float*)d_in[12];
  const float* Wsc  = (const float*)d_in[13];
  const float* Wrsc = (const float*)d_in[14];
  const float* bsc  = (const float*)d_in[15];
  const float* gsc  = (const float*)d_in[16];
  const float* besc = (const float*)d_in[17];
  float* out = (float*)d_out;

  const int* src = eidx;
  const int* dst = eidx + N_EDGES;

  char* base = (char*)d_ws;
  size_t off = 0;
  auto alloc = [&](size_t bytes) -> char* {
    char* p = base + off;
    off += (bytes + 255) & ~(size_t)255;
    return p;
  };
  int* cnt2   = (int*)alloc((size_t)NBINS * 4);
  int* ecnt   = (int*)alloc((size_t)N_NODES * 4);      // adjacent to cnt2: one memset
  int* cur2   = (int*)alloc((size_t)NBINS * 4);
  int* rowptr2= (int*)alloc((size_t)(NBINS + 1) * 4);
  const int NB_SCAN = CDIV(NBINS, 2048);
  int* bsum   = (int*)alloc((size_t)(NB_SCAN + 1) * 4);
  int* boff   = (int*)alloc((size_t)(NB_SCAN + 1) * 4);
  int* erowptr= (int*)alloc((size_t)(N_NODES + 1) * 4);
  int* ecur   = (int*)alloc((size_t)N_NODES * 4);
  int* eorder = (int*)alloc((size_t)N_EDGES * 4);
  int2* pairs = (int2*)alloc((size_t)NPAIRS * 8);
  unsigned short* xb    = (unsigned short*)alloc((size_t)N_NODES * CIN * 2);
  unsigned short* hb    = (unsigned short*)alloc((size_t)N_NODES * COUT * 2);
  unsigned short* W1aug = (unsigned short*)alloc((size_t)256 * KTOT * CIN * 2);
  unsigned short* W2t   = (unsigned short*)alloc((size_t)COUT * KTOT * COUT * 2);
  unsigned short* rootBt= (unsigned short*)alloc((size_t)256 * CIN * 2);
  unsigned short* Wr2t  = (unsigned short*)alloc((size_t)COUT * COUT * 2);
  float* msgaug= (float*)alloc((size_t)N_NODES * 256 * 4);    // conv1+shortcut (zeroed)
  float* msg2  = (float*)alloc((size_t)N_NODES * COUT * 4);   // conv2 (zeroed, adjacent)
  float* h1    = (float*)alloc((size_t)N_NODES * COUT * 4);
  float* h2r   = (float*)alloc((size_t)N_NODES * COUT * 4);
  float* sraw  = (float*)alloc((size_t)N_NODES * COUT * 4);
  float* stats = (float*)alloc(6 * 128 * 4);
  (void)ws_size;
  const int SPLIT = 10;  // 9 slices x 13 spline bins + slice 9: 8 bins + root step

  // one memset covers cnt2 + ecnt (adjacent allocations)
  hipMemsetAsync(cnt2, 0, (size_t)((char*)ecnt - (char*)cnt2) + (size_t)N_NODES * 4, stream);
  hipMemsetAsync(msgaug, 0, (size_t)N_NODES * (256 + 128) * 4, stream); // msgaug + msg2

  // edge CSR: dst-sorted edge permutation (write locality for the pair sort)
  ecount<<<CDIV(N_EDGES, 256), 256, 0, stream>>>(dst, ecnt, N_EDGES);
  escan<<<1, 256, 0, stream>>>(ecnt, erowptr, ecur, N_NODES);
  efill<<<CDIV(N_EDGES, 256), 256, 0, stream>>>(dst, ecur, eorder, N_EDGES);

  // (dst,k)-pair counting sort in dst-sorted order; weights carry 1/deg
  pair_count<<<CDIV(N_EDGES, 256), 256, 0, stream>>>(eorder, dst, attr, cnt2, N_EDGES);
  scan_a<<<NB_SCAN, 256, 0, stream>>>(cnt2, bsum, NBINS);
  scan_b<<<1, 256, 0, stream>>>(bsum, boff, NB_SCAN, rowptr2, NBINS, stats);
  scan_c<<<NB_SCAN, 256, 0, stream>>>(cnt2, boff, rowptr2, cur2, NBINS);
  pair_fill<<<CDIV(N_EDGES, 256), 256, 0, stream>>>(eorder, src, dst, attr, erowptr,
                                                    cur2, pairs, N_EDGES);

  const long CONV_TOT = 640000L + 1024000L + 2048000L + 8192 + 8192 + 16384 + 1024000L;
  convert_all<<<CDIV(CONV_TOT, 256), 256, 0, stream>>>(x, W1, W2, Wr1, Wrsc, Wr2, Wsc,
                                                       xb, W1aug, W2t, rootBt, Wr2t);

  const int GX = CDIV(N_NODES, 128);
  // ---- conv1 + shortcut spline + both root GEMMs, all fused ----
  for (int z = 0; z < SPLIT; z++) {
    int kb0 = z * 13;
    int kbn = (125 - kb0 < 13) ? (125 - kb0) : 13;
    int do_root = (z == SPLIT - 1);
    fused_conv<64, 256><<<dim3(GX, 1), 256, 0, stream>>>(
        xb, rowptr2, pairs, W1aug, rootBt, msgaug, N_NODES, kb0, kbn, do_root);
  }
  finalize_stats<<<64, 256, 0, stream>>>(msgaug, b1, h1, stats, N_NODES);
  bn_elu_kernel<<<CDIV(N_NODES * COUT, 256), 256, 0, stream>>>(h1, hb, stats, g1, be1, N_NODES);

  // ---- conv2 fused ----
  for (int z = 0; z < SPLIT; z++) {
    int kb0 = z * 13;
    int kbn = (125 - kb0 < 13) ? (125 - kb0) : 13;
    int do_root = (z == SPLIT - 1);
    fused_conv<128, 128><<<dim3(GX, 1), 256, 0, stream>>>(
        hb, rowptr2, pairs, W2t, Wr2t, msg2, N_NODES, kb0, kbn, do_root);
  }
  finalize2_dual<<<64, 256, 0, stream>>>(msg2, b2, msgaug, bsc, h2r, sraw,
                                         stats + 256, stats + 512, N_NODES);

  // ---- output ----
  final_out_kernel<<<CDIV(N_NODES * COUT, 256), 256, 0, stream>>>(
      h2r, sraw, stats + 256, stats + 512, g2, be2, gsc, besc, out, N_NODES);
}

// Round 10
// 803.441 us; speedup vs baseline: 4.6925x; 4.6925x over previous
//
#include <hip/hip_runtime.h>

#define N_NODES 10000
#define N_EDGES 160000
#define CIN 64
#define COUT 128
#define KTOT 125
#define NBINS (N_NODES * KTOT)          // 1,250,000
#define NPAIRS (N_EDGES * 8)            // 1,280,000
#define EPS 1e-5f

#define CDIV(a,b) (((a)+(b)-1)/(b))

typedef __attribute__((ext_vector_type(8))) short short8;
typedef __attribute__((ext_vector_type(4))) float floatx4;

static __device__ __forceinline__ unsigned short f2b(float f) {
  union { float f; unsigned u; } v; v.f = f;
  unsigned r = v.u + 0x7FFFu + ((v.u >> 16) & 1u);
  return (unsigned short)(r >> 16);
}
static __device__ __forceinline__ float b2f(unsigned short u) {
  union { unsigned u; float f; } v; v.u = ((unsigned)u) << 16;
  return v.f;
}

typedef __attribute__((address_space(1))) const unsigned int guint;
typedef __attribute__((address_space(3))) unsigned int luint;
static __device__ __forceinline__ void ld_g2l16(const void* g, void* l) {
  __builtin_amdgcn_global_load_lds((guint*)g, (luint*)l, 16, 0, 0);
}

// ---------------- edge CSR (dst-sorted edge order) ----------
__global__ void ecount(const int* __restrict__ dst, int* __restrict__ ecnt, int E) {
  int e = blockIdx.x * 256 + threadIdx.x;
  if (e < E) atomicAdd(&ecnt[dst[e]], 1);
}

// single-block exclusive scan over n=10000; seeds ecur; zeroes stats; caps rowptr2
__global__ void escan(const int* __restrict__ cnt, int* __restrict__ rowptr,
                      int* __restrict__ cur, int n, int* __restrict__ rowptr2,
                      float* __restrict__ stats) {
  for (int i = threadIdx.x; i < 6 * 128; i += 256) stats[i] = 0.f;
  __shared__ int buf[256];
  __shared__ int carry;
  if (threadIdx.x == 0) { carry = 0; rowptr[0] = 0; rowptr2[NBINS] = NPAIRS; }
  __syncthreads();
  for (int base = 0; base < n; base += 256) {
    int i = base + threadIdx.x;
    int v = (i < n) ? cnt[i] : 0;
    buf[threadIdx.x] = v;
    __syncthreads();
    for (int s = 1; s < 256; s <<= 1) {
      int t = (threadIdx.x >= s) ? buf[threadIdx.x - s] : 0;
      __syncthreads();
      buf[threadIdx.x] += t;
      __syncthreads();
    }
    if (i < n) {
      int incl = carry + buf[threadIdx.x];
      rowptr[i + 1] = incl;
      cur[i] = incl - v;
    }
    __syncthreads();
    if (threadIdx.x == 255) carry += buf[255];
    __syncthreads();
  }
}

__global__ void efill(const int* __restrict__ dst, int* __restrict__ ecur,
                      int* __restrict__ eorder, int E) {
  int e = blockIdx.x * 256 + threadIdx.x;
  if (e >= E) return;
  int pos = atomicAdd(&ecur[dst[e]], 1);
  eorder[pos] = e;
}

// ---------------- build_pairs: one wave per node ----------------
// Node n's pair block starts at exactly 8*erowptr[n] (8 pairs per edge), so no
// global scan over bins is needed: per-node 125-bin LDS histogram + wave prefix
// scan gives rowptr2 and placement cursors directly. Weights carry 1/deg.
__global__ __launch_bounds__(256) void build_pairs(
    const int* __restrict__ eorder, const int* __restrict__ erowptr,
    const int* __restrict__ src, const float* __restrict__ attr,
    int* __restrict__ rowptr2, int2* __restrict__ pairs) {
  __shared__ int hist_s[4][126];
  __shared__ int cur_s[4][126];
  int w = threadIdx.x >> 6, lane = threadIdx.x & 63;
  int node = blockIdx.x * 4 + w;
  if (node >= N_NODES) return;
  int* hist = hist_s[w];
  int* cur = cur_s[w];
  hist[lane] = 0;
  if (lane < 61) hist[64 + lane] = 0;
  __builtin_amdgcn_s_waitcnt(0);
  int e0 = erowptr[node], e1 = erowptr[node + 1];
  int deg = e1 - e0;
  float invdeg = 1.0f / fmaxf((float)deg, 1.0f);
  int sub_e = lane >> 3, corner = lane & 7;
  int bit0 = corner & 1, bit1 = (corner >> 1) & 1, bit2 = (corner >> 2) & 1;
  // phase 1: k-histogram (8 edges x 8 corners per pass)
  for (int base = 0; base < deg; base += 8) {
    int ei = base + sub_e;
    if (ei < deg) {
      int e = eorder[e0 + ei];
      float v0 = attr[e * 3 + 0] * 4.f;
      float v1 = attr[e * 3 + 1] * 4.f;
      float v2 = attr[e * 3 + 2] * 4.f;
      int i0 = (int)floorf(v0), i1 = (int)floorf(v1), i2 = (int)floorf(v2);
      int k0 = min(max(i0 + bit0, 0), 4);
      int k1 = min(max(i1 + bit1, 0), 4);
      int k2 = min(max(i2 + bit2, 0), 4);
      atomicAdd(&hist[k0 * 25 + k1 * 5 + k2], 1);
    }
  }
  __builtin_amdgcn_s_waitcnt(0);
  // wave exclusive scan over 125 bins (lane owns bin lane and bin 64+lane)
  int v0 = hist[lane];
  int v1 = (lane < 61) ? hist[64 + lane] : 0;
  int s0 = v0;
#pragma unroll
  for (int d = 1; d < 64; d <<= 1) {
    int t = __shfl_up(s0, d, 64);
    if (lane >= d) s0 += t;
  }
  int excl0 = s0 - v0;
  int tot0 = __shfl(s0, 63, 64);
  int s1 = v1;
#pragma unroll
  for (int d = 1; d < 64; d <<= 1) {
    int t = __shfl_up(s1, d, 64);
    if (lane >= d) s1 += t;
  }
  int excl1 = s1 - v1 + tot0;
  int basep = e0 * 8;
  long rbase = (long)node * KTOT;
  rowptr2[rbase + lane] = basep + excl0;
  cur[lane] = basep + excl0;
  if (lane < 61) {
    rowptr2[rbase + 64 + lane] = basep + excl1;
    cur[64 + lane] = basep + excl1;
  }
  __builtin_amdgcn_s_waitcnt(0);
  // phase 2: place pairs
  for (int base = 0; base < deg; base += 8) {
    int ei = base + sub_e;
    if (ei < deg) {
      int e = eorder[e0 + ei];
      float v0f = attr[e * 3 + 0] * 4.f;
      float v1f = attr[e * 3 + 1] * 4.f;
      float v2f = attr[e * 3 + 2] * 4.f;
      float b0f = floorf(v0f), b1f = floorf(v1f), b2f_ = floorf(v2f);
      float f0 = v0f - b0f, f1 = v1f - b1f, f2 = v2f - b2f_;
      int i0 = (int)b0f, i1 = (int)b1f, i2 = (int)b2f_;
      float wv = (bit0 ? f0 : 1.f - f0) * (bit1 ? f1 : 1.f - f1) * (bit2 ? f2 : 1.f - f2);
      int k0 = min(max(i0 + bit0, 0), 4);
      int k1 = min(max(i1 + bit1, 0), 4);
      int k2 = min(max(i2 + bit2, 0), 4);
      int pos = atomicAdd(&cur[k0 * 25 + k1 * 5 + k2], 1);
      int2 rec; rec.x = src[e]; rec.y = __float_as_int(wv * invdeg);
      pairs[pos] = rec;
    }
  }
}

// ---------------- one-shot convert: xb + all weight transposes ----------------
__global__ void convert_all(const float* __restrict__ x, const float* __restrict__ W1,
                            const float* __restrict__ W2, const float* __restrict__ Wr1,
                            const float* __restrict__ Wrsc, const float* __restrict__ Wr2,
                            const float* __restrict__ Wsc,
                            unsigned short* __restrict__ xb, unsigned short* __restrict__ W1aug,
                            unsigned short* __restrict__ W2t, unsigned short* __restrict__ rootBt,
                            unsigned short* __restrict__ Wr2t) {
  long i = (long)blockIdx.x * 256 + threadIdx.x;
  const long n0 = 640000, n1 = n0 + 1024000, n2 = n1 + 2048000,
             n3 = n2 + 8192, n4 = n3 + 8192, n5 = n4 + 16384, n6 = n5 + 1024000;
  if (i < n0) {
    xb[i] = f2b(x[i]);
  } else if (i < n1) {
    long j = i - n0; int k = (int)(j >> 7), c = (int)(j & 127);
    W1aug[(long)c * 8000 + k] = f2b(W1[j]);
  } else if (i < n2) {
    long j = i - n1; int k = (int)(j >> 7), c = (int)(j & 127);
    W2t[(long)c * 16000 + k] = f2b(W2[j]);
  } else if (i < n3) {
    long j = i - n2; int k = (int)(j >> 7), c = (int)(j & 127);
    rootBt[c * 64 + k] = f2b(Wr1[j]);
  } else if (i < n4) {
    long j = i - n3; int k = (int)(j >> 7), c = (int)(j & 127);
    rootBt[(128 + c) * 64 + k] = f2b(Wrsc[j]);
  } else if (i < n5) {
    long j = i - n4; int k = (int)(j >> 7), c = (int)(j & 127);
    Wr2t[c * 128 + k] = f2b(Wr2[j]);
  } else if (i < n6) {
    long j = i - n5;
    int c = (int)(j / 8000), kk = (int)(j % 8000);
    W1aug[(long)(128 + c) * 8000 + kk] = f2b(Wsc[(kk & 63) * 128 + c]);
  }
}

// ---------------- scatter: one wave per 8 consecutive bins, register accumulate --
template<int C>
__global__ __launch_bounds__(256) void scatter_bins(
    const unsigned short* __restrict__ Xb, const int* __restrict__ rowptr2,
    const int2* __restrict__ pairs,
    unsigned short* __restrict__ accb, int bin0, int nbins_chunk) {
  int wb0 = (blockIdx.x * 4 + (threadIdx.x >> 6)) * 8;
  if (wb0 >= nbins_chunk) return;
  int lane = threadIdx.x & 63;
  int bin = bin0 + wb0;
  int bounds = 0;
  if (lane < 9) bounds = rowptr2[bin + lane];
  int b[9];
#pragma unroll
  for (int j = 0; j < 9; j++) b[j] = __shfl(bounds, j, 64);
#pragma unroll
  for (int j = 0; j < 8; j++) {
    int wb = wb0 + j;
    if (wb >= nbins_chunk) break;
    float a0 = 0.f, a1 = 0.f;
    for (int p = b[j]; p < b[j + 1]; p++) {
      int2 rec = pairs[p];
      float w = __int_as_float(rec.y);
      if (C == 64) {
        a0 += w * b2f(Xb[(long)rec.x * 64 + lane]);
      } else {
        unsigned u = *(const unsigned*)(Xb + (long)rec.x * 128 + lane * 2);
        a0 += w * b2f((unsigned short)(u & 0xffffu));
        a1 += w * b2f((unsigned short)(u >> 16));
      }
    }
    if (C == 64) {
      accb[(long)wb * 64 + lane] = f2b(a0);
    } else {
      unsigned pk = (unsigned)f2b(a0) | ((unsigned)f2b(a1) << 16);
      *(unsigned*)(accb + (long)wb * 128 + lane * 2) = pk;
    }
  }
}

// ---------------- LDS-staged MFMA GEMM, 128 output cols ----------------
template<int NCOLS, bool ATOMIC>
__global__ __launch_bounds__(256, 2) void gemm_tile(const unsigned short* __restrict__ A,
                                                    const unsigned short* __restrict__ Bt,
                                                    float* __restrict__ C, int M, int K) {
  __shared__ unsigned short As[128 * 32];
  __shared__ unsigned short Bs[128 * 32];
  int wid = threadIdx.x >> 6, lane = threadIdx.x & 63;
  int row0 = blockIdx.x * 128;
  int nslice = gridDim.y;
  int kslice = CDIV(K / 32, nslice) * 32;
  int kbeg = blockIdx.y * kslice;
  int kend = kbeg + kslice; if (kend > K) kend = K;
  if (kbeg >= K) return;

  int sub = lane & 3;
  int rload = lane >> 2;
  int q = lane >> 4, m16 = lane & 15;

  floatx4 acc[2][8];
#pragma unroll
  for (int t = 0; t < 2; t++)
#pragma unroll
    for (int c = 0; c < 8; c++) acc[t][c] = (floatx4){0.f, 0.f, 0.f, 0.f};

  for (int k0 = kbeg; k0 < kend; k0 += 32) {
    __syncthreads();
#pragma unroll
    for (int j = 0; j < 2; j++) {
      int tr = (wid * 2 + j) * 16 + rload;
      int gr = row0 + tr; if (gr >= M) gr = M - 1;
      ld_g2l16(A + (long)gr * K + k0 + sub * 8, As + (wid * 2 + j) * 512);
      ld_g2l16(Bt + (long)tr * K + k0 + sub * 8, Bs + (wid * 2 + j) * 512);
    }
    __syncthreads();
#pragma unroll
    for (int t = 0; t < 2; t++) {
      int arow = wid * 32 + t * 16 + m16;
      short8 a = *(const short8*)(As + arow * 32 + q * 8);
#pragma unroll
      for (int c = 0; c < 8; c++) {
        short8 b = *(const short8*)(Bs + (c * 16 + m16) * 32 + q * 8);
        acc[t][c] = __builtin_amdgcn_mfma_f32_16x16x32_bf16(a, b, acc[t][c], 0, 0, 0);
      }
    }
  }

#pragma unroll
  for (int t = 0; t < 2; t++) {
#pragma unroll
    for (int c = 0; c < 8; c++) {
#pragma unroll
      for (int r = 0; r < 4; r++) {
        int orow = row0 + wid * 32 + t * 16 + q * 4 + r;
        if (orow < M) {
          float* p = &C[(long)orow * NCOLS + c * 16 + m16];
          if (ATOMIC) atomicAdd(p, acc[t][c][r]);
          else *p = acc[t][c][r];
        }
      }
    }
  }
}

// ---------------- 128x256 tile GEMM (conv1+shortcut in one A pass) ----------------
template<bool ATOMIC>
__global__ __launch_bounds__(256, 2) void gemm_tile_w256(const unsigned short* __restrict__ A,
                                                         const unsigned short* __restrict__ Bt,
                                                         float* __restrict__ C, int M, int K) {
  __shared__ unsigned short As[128 * 32];
  __shared__ unsigned short Bs[256 * 32];
  int wid = threadIdx.x >> 6, lane = threadIdx.x & 63;
  int row0 = blockIdx.x * 128;
  int nslice = gridDim.y;
  int kslice = CDIV(K / 32, nslice) * 32;
  int kbeg = blockIdx.y * kslice;
  int kend = kbeg + kslice; if (kend > K) kend = K;
  if (kbeg >= K) return;

  int sub = lane & 3;
  int rload = lane >> 2;
  int q = lane >> 4, m16 = lane & 15;

  floatx4 acc[2][16];
#pragma unroll
  for (int t = 0; t < 2; t++)
#pragma unroll
    for (int c = 0; c < 16; c++) acc[t][c] = (floatx4){0.f, 0.f, 0.f, 0.f};

  for (int k0 = kbeg; k0 < kend; k0 += 32) {
    __syncthreads();
#pragma unroll
    for (int j = 0; j < 2; j++) {
      int tr = (wid * 2 + j) * 16 + rload;
      int gr = row0 + tr; if (gr >= M) gr = M - 1;
      ld_g2l16(A + (long)gr * K + k0 + sub * 8, As + (wid * 2 + j) * 512);
    }
#pragma unroll
    for (int j = 0; j < 4; j++) {
      int tr = (wid * 4 + j) * 16 + rload;
      ld_g2l16(Bt + (long)tr * K + k0 + sub * 8, Bs + (wid * 4 + j) * 512);
    }
    __syncthreads();
#pragma unroll
    for (int t = 0; t < 2; t++) {
      int arow = wid * 32 + t * 16 + m16;
      short8 a = *(const short8*)(As + arow * 32 + q * 8);
#pragma unroll
      for (int c = 0; c < 16; c++) {
        short8 b = *(const short8*)(Bs + (c * 16 + m16) * 32 + q * 8);
        acc[t][c] = __builtin_amdgcn_mfma_f32_16x16x32_bf16(a, b, acc[t][c], 0, 0, 0);
      }
    }
  }

#pragma unroll
  for (int t = 0; t < 2; t++) {
#pragma unroll
    for (int c = 0; c < 16; c++) {
#pragma unroll
      for (int r = 0; r < 4; r++) {
        int orow = row0 + wid * 32 + t * 16 + q * 4 + r;
        if (orow < M) {
          float* p = &C[(long)orow * 256 + c * 16 + m16];
          if (ATOMIC) atomicAdd(p, acc[t][c][r]);
          else *p = acc[t][c][r];
        }
      }
    }
  }
}

// ---------------- epilogues (weights pre-divided by deg -> no deg here) --------
__global__ void finalize_stats(const float* __restrict__ msgaug, const float* __restrict__ root,
                               const float* __restrict__ bias,
                               float* __restrict__ out, float* __restrict__ stats, int n) {
  int c = threadIdx.x & 127;
  float bv = bias[c];
  float s = 0.f, s2 = 0.f;
  long tot = (long)n * COUT;
  long stride = (long)gridDim.x * 256;
  for (long i = (long)blockIdx.x * 256 + threadIdx.x; i < tot; i += stride) {
    int r = (int)(i >> 7);
    float v = msgaug[(long)r * 256 + c] + root[(long)r * 256 + c] + bv;
    out[i] = v;
    s += v; s2 += v * v;
  }
  __shared__ float ls[256], ls2[256];
  ls[threadIdx.x] = s; ls2[threadIdx.x] = s2;
  __syncthreads();
  if (threadIdx.x < 128) {
    atomicAdd(&stats[c], ls[threadIdx.x] + ls[threadIdx.x + 128]);
    atomicAdd(&stats[128 + c], ls2[threadIdx.x] + ls2[threadIdx.x + 128]);
  }
}

__global__ void finalize2_dual(const float* __restrict__ msg2, const float* __restrict__ rootb2,
                               const float* __restrict__ b2, const float* __restrict__ msgaug,
                               const float* __restrict__ rootb, const float* __restrict__ bsc,
                               float* __restrict__ h2r, float* __restrict__ sraw,
                               float* __restrict__ stats2, float* __restrict__ statssc, int n) {
  int c = threadIdx.x & 127;
  float bv2 = b2[c], bvsc = bsc[c];
  float sa = 0.f, sb = 0.f, ta = 0.f, tb = 0.f;
  long tot = (long)n * COUT;
  long stride = (long)gridDim.x * 256;
  for (long i = (long)blockIdx.x * 256 + threadIdx.x; i < tot; i += stride) {
    int r = (int)(i >> 7);
    float v2 = msg2[i] + rootb2[i] + bv2;
    h2r[i] = v2;
    sa += v2; sb += v2 * v2;
    float vs = msgaug[(long)r * 256 + 128 + c] + rootb[(long)r * 256 + 128 + c] + bvsc;
    sraw[i] = vs;
    ta += vs; tb += vs * vs;
  }
  __shared__ float l0[256], l1[256], l2[256], l3[256];
  l0[threadIdx.x] = sa; l1[threadIdx.x] = sb; l2[threadIdx.x] = ta; l3[threadIdx.x] = tb;
  __syncthreads();
  if (threadIdx.x < 128) {
    atomicAdd(&stats2[c], l0[threadIdx.x] + l0[threadIdx.x + 128]);
    atomicAdd(&stats2[128 + c], l1[threadIdx.x] + l1[threadIdx.x + 128]);
    atomicAdd(&statssc[c], l2[threadIdx.x] + l2[threadIdx.x + 128]);
    atomicAdd(&statssc[128 + c], l3[threadIdx.x] + l3[threadIdx.x + 128]);
  }
}

__global__ void bn_elu_kernel(float* __restrict__ h, unsigned short* __restrict__ hb,
                              const float* __restrict__ stats, const float* __restrict__ g,
                              const float* __restrict__ be, int n) {
  long i = (long)blockIdx.x * 256 + threadIdx.x;
  if (i >= (long)n * COUT) return;
  int c = (int)(i & 127);
  float inv_n = 1.0f / n;
  float mu = stats[c] * inv_n;
  float var = stats[128 + c] * inv_n - mu * mu;
  float v = (h[i] - mu) * rsqrtf(var + EPS) * g[c] + be[c];
  v = v > 0.f ? v : expm1f(v);
  h[i] = v;
  hb[i] = f2b(v);
}

__global__ void final_out_kernel(const float* __restrict__ h2, const float* __restrict__ sraw,
                                 const float* __restrict__ st2, const float* __restrict__ stsc,
                                 const float* __restrict__ g2, const float* __restrict__ be2,
                                 const float* __restrict__ gsc, const float* __restrict__ besc,
                                 float* __restrict__ out, int n) {
  long i = (long)blockIdx.x * 256 + threadIdx.x;
  if (i >= (long)n * COUT) return;
  int c = (int)(i & 127);
  float inv_n = 1.0f / n;
  float mu2 = st2[c] * inv_n;
  float var2 = st2[128 + c] * inv_n - mu2 * mu2;
  float a = (h2[i] - mu2) * rsqrtf(var2 + EPS) * g2[c] + be2[c];
  float musc = stsc[c] * inv_n;
  float varsc = stsc[128 + c] * inv_n - musc * musc;
  float b = (sraw[i] - musc) * rsqrtf(varsc + EPS) * gsc[c] + besc[c];
  float v = a + b;
  out[i] = v > 0.f ? v : expm1f(v);
}

// ---------------- host ----------------
extern "C" void kernel_launch(void* const* d_in, const int* in_sizes, int n_in,
                              void* d_out, int out_size, void* d_ws, size_t ws_size,
                              hipStream_t stream) {
  const float* x    = (const float*)d_in[0];
  const int*   eidx = (const int*)d_in[1];
  const float* attr = (const float*)d_in[2];
  const float* W1   = (const float*)d_in[3];
  const float* Wr1  = (const float*)d_in[4];
  const float* b1   = (const float*)d_in[5];
  const float* g1   = (const float*)d_in[6];
  const float* be1  = (const float*)d_in[7];
  const float* W2   = (const float*)d_in[8];
  const float* Wr2  = (const float*)d_in[9];
  const float* b2   = (const float*)d_in[10];
  const float* g2   = (const float*)d_in[11];
  const float* be2  = (const float*)d_in[12];
  const float* Wsc  = (const float*)d_in[13];
  const float* Wrsc = (const float*)d_in[14];
  const float* bsc  = (const float*)d_in[15];
  const float* gsc  = (const float*)d_in[16];
  const float* besc = (const float*)d_in[17];
  float* out = (float*)d_out;

  const int* src = eidx;
  const int* dst = eidx + N_EDGES;

  char* base = (char*)d_ws;
  size_t off = 0;
  auto alloc = [&](size_t bytes) -> char* {
    char* p = base + off;
    off += (bytes + 255) & ~(size_t)255;
    return p;
  };
  int* ecnt   = (int*)alloc((size_t)N_NODES * 4);
  int* erowptr= (int*)alloc((size_t)(N_NODES + 1) * 4);
  int* ecur   = (int*)alloc((size_t)N_NODES * 4);
  int* eorder = (int*)alloc((size_t)N_EDGES * 4);
  int* rowptr2= (int*)alloc((size_t)(NBINS + 1) * 4);
  int2* pairs = (int2*)alloc((size_t)NPAIRS * 8);
  unsigned short* xb    = (unsigned short*)alloc((size_t)N_NODES * CIN * 2);
  unsigned short* hb    = (unsigned short*)alloc((size_t)N_NODES * COUT * 2);
  unsigned short* W1aug = (unsigned short*)alloc((size_t)256 * KTOT * CIN * 2);
  unsigned short* W2t   = (unsigned short*)alloc((size_t)COUT * KTOT * COUT * 2);
  unsigned short* rootBt= (unsigned short*)alloc((size_t)256 * CIN * 2);
  unsigned short* Wr2t  = (unsigned short*)alloc((size_t)COUT * COUT * 2);
  float* msgaug= (float*)alloc((size_t)N_NODES * 256 * 4);    // conv1+shortcut (zeroed)
  float* msg2  = (float*)alloc((size_t)N_NODES * COUT * 4);   // conv2 (zeroed, adjacent)
  float* rootb = (float*)alloc((size_t)N_NODES * 256 * 4);    // [Wr1 | Wrsc]
  float* rootb2= (float*)alloc((size_t)N_NODES * COUT * 4);
  float* h1    = (float*)alloc((size_t)N_NODES * COUT * 4);
  float* h2r   = (float*)alloc((size_t)N_NODES * COUT * 4);
  float* sraw  = (float*)alloc((size_t)N_NODES * COUT * 4);
  float* stats = (float*)alloc(6 * 128 * 4);
  unsigned short* accb = (unsigned short*)(base + off);
  size_t avail = (ws_size > off) ? (ws_size - off) : 0;
  size_t per_node = (size_t)KTOT * COUT * 2;
  size_t chmax = avail / per_node;
  int CH = (int)((chmax < (size_t)N_NODES) ? chmax : (size_t)N_NODES);
  if (CH < 1) CH = 1;
  const int SPLIT = 10;

  hipMemsetAsync(ecnt, 0, (size_t)N_NODES * 4, stream);
  hipMemsetAsync(msgaug, 0, (size_t)N_NODES * (256 + 128) * 4, stream); // msgaug + msg2

  // edge CSR: dst-sorted edge permutation
  ecount<<<CDIV(N_EDGES, 256), 256, 0, stream>>>(dst, ecnt, N_EDGES);
  escan<<<1, 256, 0, stream>>>(ecnt, erowptr, ecur, N_NODES, rowptr2, stats);
  efill<<<CDIV(N_EDGES, 256), 256, 0, stream>>>(dst, ecur, eorder, N_EDGES);

  // per-node pair build: replaces pair_count + 3-kernel scan + pair_fill
  build_pairs<<<CDIV(N_NODES, 4), 256, 0, stream>>>(eorder, erowptr, src, attr,
                                                    rowptr2, pairs);

  const long CONV_TOT = 640000L + 1024000L + 2048000L + 8192 + 8192 + 16384 + 1024000L;
  convert_all<<<CDIV(CONV_TOT, 256), 256, 0, stream>>>(x, W1, W2, Wr1, Wrsc, Wr2, Wsc,
                                                       xb, W1aug, W2t, rootBt, Wr2t);

  // ---- conv1 (+ shortcut spline via augmented cols 128..255, single A pass) ----
  for (int c0 = 0; c0 < N_NODES; c0 += CH) {
    int cm = (N_NODES - c0 < CH) ? (N_NODES - c0) : CH;
    int nbc = cm * KTOT;
    scatter_bins<64><<<CDIV(nbc, 32), 256, 0, stream>>>(xb, rowptr2, pairs, accb,
                                                        c0 * KTOT, nbc);
    dim3 g(CDIV(cm, 128), SPLIT);
    gemm_tile_w256<true><<<g, 256, 0, stream>>>(accb, W1aug, msgaug + (size_t)c0 * 256,
                                                cm, KTOT * CIN);
  }
  gemm_tile_w256<false><<<dim3(CDIV(N_NODES, 128), 1), 256, 0, stream>>>(
      xb, rootBt, rootb, N_NODES, CIN);
  finalize_stats<<<64, 256, 0, stream>>>(msgaug, rootb, b1, h1, stats, N_NODES);
  bn_elu_kernel<<<CDIV(N_NODES * COUT, 256), 256, 0, stream>>>(h1, hb, stats, g1, be1, N_NODES);

  // ---- conv2 ----
  for (int c0 = 0; c0 < N_NODES; c0 += CH) {
    int cm = (N_NODES - c0 < CH) ? (N_NODES - c0) : CH;
    int nbc = cm * KTOT;
    scatter_bins<128><<<CDIV(nbc, 32), 256, 0, stream>>>(hb, rowptr2, pairs, accb,
                                                         c0 * KTOT, nbc);
    dim3 g(CDIV(cm, 128), SPLIT);
    gemm_tile<COUT, true><<<g, 256, 0, stream>>>(accb, W2t, msg2 + (size_t)c0 * COUT,
                                                 cm, KTOT * COUT);
  }
  gemm_tile<COUT, false><<<dim3(CDIV(N_NODES, 128), 1), 256, 0, stream>>>(
      hb, Wr2t, rootb2, N_NODES, COUT);
  finalize2_dual<<<64, 256, 0, stream>>>(msg2, rootb2, b2, msgaug, rootb, bsc,
                                         h2r, sraw, stats + 256, stats + 512, N_NODES);

  // ---- output ----
  final_out_kernel<<<CDIV(N_NODES * COUT, 256), 256, 0, stream>>>(
      h2r, sraw, stats + 256, stats + 512, g2, be2, gsc, besc, out, N_NODES);
}

// Round 11
// 802.244 us; speedup vs baseline: 4.6995x; 1.0015x over previous
//
#include <hip/hip_runtime.h>

#define N_NODES 10000
#define N_EDGES 160000
#define CIN 64
#define COUT 128
#define KTOT 125
#define NBINS (N_NODES * KTOT)          // 1,250,000
#define NPAIRS (N_EDGES * 8)            // 1,280,000
#define EPS 1e-5f

#define CDIV(a,b) (((a)+(b)-1)/(b))

typedef __attribute__((ext_vector_type(8))) short short8;
typedef __attribute__((ext_vector_type(4))) float floatx4;

static __device__ __forceinline__ unsigned short f2b(float f) {
  union { float f; unsigned u; } v; v.f = f;
  unsigned r = v.u + 0x7FFFu + ((v.u >> 16) & 1u);
  return (unsigned short)(r >> 16);
}
static __device__ __forceinline__ float b2f(unsigned short u) {
  union { unsigned u; float f; } v; v.u = ((unsigned)u) << 16;
  return v.f;
}

typedef __attribute__((address_space(1))) const unsigned int guint;
typedef __attribute__((address_space(3))) unsigned int luint;
static __device__ __forceinline__ void ld_g2l16(const void* g, void* l) {
  __builtin_amdgcn_global_load_lds((guint*)g, (luint*)l, 16, 0, 0);
}

// ---------------- edge CSR (dst-sorted edge order) ----------
__global__ void ecount(const int* __restrict__ dst, int* __restrict__ ecnt, int E) {
  int e = blockIdx.x * 256 + threadIdx.x;
  if (e < E) atomicAdd(&ecnt[dst[e]], 1);
}

// single-block exclusive scan over n=10000; seeds ecur; zeroes stats; caps rowptr2
__global__ void escan(const int* __restrict__ cnt, int* __restrict__ rowptr,
                      int* __restrict__ cur, int n, int* __restrict__ rowptr2,
                      float* __restrict__ stats) {
  for (int i = threadIdx.x; i < 6 * 128; i += 256) stats[i] = 0.f;
  __shared__ int buf[256];
  __shared__ int carry;
  if (threadIdx.x == 0) { carry = 0; rowptr[0] = 0; rowptr2[NBINS] = NPAIRS; }
  __syncthreads();
  for (int base = 0; base < n; base += 256) {
    int i = base + threadIdx.x;
    int v = (i < n) ? cnt[i] : 0;
    buf[threadIdx.x] = v;
    __syncthreads();
    for (int s = 1; s < 256; s <<= 1) {
      int t = (threadIdx.x >= s) ? buf[threadIdx.x - s] : 0;
      __syncthreads();
      buf[threadIdx.x] += t;
      __syncthreads();
    }
    if (i < n) {
      int incl = carry + buf[threadIdx.x];
      rowptr[i + 1] = incl;
      cur[i] = incl - v;
    }
    __syncthreads();
    if (threadIdx.x == 255) carry += buf[255];
    __syncthreads();
  }
}

__global__ void efill(const int* __restrict__ dst, int* __restrict__ ecur,
                      int* __restrict__ eorder, int E) {
  int e = blockIdx.x * 256 + threadIdx.x;
  if (e >= E) return;
  int pos = atomicAdd(&ecur[dst[e]], 1);
  eorder[pos] = e;
}

// ---------------- build_pairs: one wave per node ----------------
__global__ __launch_bounds__(256) void build_pairs(
    const int* __restrict__ eorder, const int* __restrict__ erowptr,
    const int* __restrict__ src, const float* __restrict__ attr,
    int* __restrict__ rowptr2, int2* __restrict__ pairs) {
  __shared__ int hist_s[4][126];
  __shared__ int cur_s[4][126];
  int w = threadIdx.x >> 6, lane = threadIdx.x & 63;
  int node = blockIdx.x * 4 + w;
  if (node >= N_NODES) return;
  int* hist = hist_s[w];
  int* cur = cur_s[w];
  hist[lane] = 0;
  if (lane < 61) hist[64 + lane] = 0;
  __builtin_amdgcn_s_waitcnt(0);
  int e0 = erowptr[node], e1 = erowptr[node + 1];
  int deg = e1 - e0;
  float invdeg = 1.0f / fmaxf((float)deg, 1.0f);
  int sub_e = lane >> 3, corner = lane & 7;
  int bit0 = corner & 1, bit1 = (corner >> 1) & 1, bit2 = (corner >> 2) & 1;
  for (int base = 0; base < deg; base += 8) {
    int ei = base + sub_e;
    if (ei < deg) {
      int e = eorder[e0 + ei];
      float v0 = attr[e * 3 + 0] * 4.f;
      float v1 = attr[e * 3 + 1] * 4.f;
      float v2 = attr[e * 3 + 2] * 4.f;
      int i0 = (int)floorf(v0), i1 = (int)floorf(v1), i2 = (int)floorf(v2);
      int k0 = min(max(i0 + bit0, 0), 4);
      int k1 = min(max(i1 + bit1, 0), 4);
      int k2 = min(max(i2 + bit2, 0), 4);
      atomicAdd(&hist[k0 * 25 + k1 * 5 + k2], 1);
    }
  }
  __builtin_amdgcn_s_waitcnt(0);
  int v0 = hist[lane];
  int v1 = (lane < 61) ? hist[64 + lane] : 0;
  int s0 = v0;
#pragma unroll
  for (int d = 1; d < 64; d <<= 1) {
    int t = __shfl_up(s0, d, 64);
    if (lane >= d) s0 += t;
  }
  int excl0 = s0 - v0;
  int tot0 = __shfl(s0, 63, 64);
  int s1 = v1;
#pragma unroll
  for (int d = 1; d < 64; d <<= 1) {
    int t = __shfl_up(s1, d, 64);
    if (lane >= d) s1 += t;
  }
  int excl1 = s1 - v1 + tot0;
  int basep = e0 * 8;
  long rbase = (long)node * KTOT;
  rowptr2[rbase + lane] = basep + excl0;
  cur[lane] = basep + excl0;
  if (lane < 61) {
    rowptr2[rbase + 64 + lane] = basep + excl1;
    cur[64 + lane] = basep + excl1;
  }
  __builtin_amdgcn_s_waitcnt(0);
  for (int base = 0; base < deg; base += 8) {
    int ei = base + sub_e;
    if (ei < deg) {
      int e = eorder[e0 + ei];
      float v0f = attr[e * 3 + 0] * 4.f;
      float v1f = attr[e * 3 + 1] * 4.f;
      float v2f = attr[e * 3 + 2] * 4.f;
      float b0f = floorf(v0f), b1f = floorf(v1f), b2f_ = floorf(v2f);
      float f0 = v0f - b0f, f1 = v1f - b1f, f2 = v2f - b2f_;
      int i0 = (int)b0f, i1 = (int)b1f, i2 = (int)b2f_;
      float wv = (bit0 ? f0 : 1.f - f0) * (bit1 ? f1 : 1.f - f1) * (bit2 ? f2 : 1.f - f2);
      int k0 = min(max(i0 + bit0, 0), 4);
      int k1 = min(max(i1 + bit1, 0), 4);
      int k2 = min(max(i2 + bit2, 0), 4);
      int pos = atomicAdd(&cur[k0 * 25 + k1 * 5 + k2], 1);
      int2 rec; rec.x = src[e]; rec.y = __float_as_int(wv * invdeg);
      pairs[pos] = rec;
    }
  }
}

// ---------------- one-shot convert: xb + all weight transposes ----------------
__global__ void convert_all(const float* __restrict__ x, const float* __restrict__ W1,
                            const float* __restrict__ W2, const float* __restrict__ Wr1,
                            const float* __restrict__ Wrsc, const float* __restrict__ Wr2,
                            const float* __restrict__ Wsc,
                            unsigned short* __restrict__ xb, unsigned short* __restrict__ W1aug,
                            unsigned short* __restrict__ W2t, unsigned short* __restrict__ rootBt,
                            unsigned short* __restrict__ Wr2t) {
  long i = (long)blockIdx.x * 256 + threadIdx.x;
  const long n0 = 640000, n1 = n0 + 1024000, n2 = n1 + 2048000,
             n3 = n2 + 8192, n4 = n3 + 8192, n5 = n4 + 16384, n6 = n5 + 1024000;
  if (i < n0) {
    xb[i] = f2b(x[i]);
  } else if (i < n1) {
    long j = i - n0; int k = (int)(j >> 7), c = (int)(j & 127);
    W1aug[(long)c * 8000 + k] = f2b(W1[j]);
  } else if (i < n2) {
    long j = i - n1; int k = (int)(j >> 7), c = (int)(j & 127);
    W2t[(long)c * 16000 + k] = f2b(W2[j]);
  } else if (i < n3) {
    long j = i - n2; int k = (int)(j >> 7), c = (int)(j & 127);
    rootBt[c * 64 + k] = f2b(Wr1[j]);
  } else if (i < n4) {
    long j = i - n3; int k = (int)(j >> 7), c = (int)(j & 127);
    rootBt[(128 + c) * 64 + k] = f2b(Wrsc[j]);
  } else if (i < n5) {
    long j = i - n4; int k = (int)(j >> 7), c = (int)(j & 127);
    Wr2t[c * 128 + k] = f2b(Wr2[j]);
  } else if (i < n6) {
    long j = i - n5;
    int c = (int)(j / 8000), kk = (int)(j % 8000);
    W1aug[(long)(128 + c) * 8000 + kk] = f2b(Wsc[(kk & 63) * 128 + c]);
  }
}

// ---------------- scatter: one wave per 8 consecutive bins, register accumulate --
template<int C>
__global__ __launch_bounds__(256) void scatter_bins(
    const unsigned short* __restrict__ Xb, const int* __restrict__ rowptr2,
    const int2* __restrict__ pairs,
    unsigned short* __restrict__ accb, int bin0, int nbins_chunk) {
  int wb0 = (blockIdx.x * 4 + (threadIdx.x >> 6)) * 8;
  if (wb0 >= nbins_chunk) return;
  int lane = threadIdx.x & 63;
  int bin = bin0 + wb0;
  int bounds = 0;
  if (lane < 9) bounds = rowptr2[bin + lane];
  int b[9];
#pragma unroll
  for (int j = 0; j < 9; j++) b[j] = __shfl(bounds, j, 64);
#pragma unroll
  for (int j = 0; j < 8; j++) {
    int wb = wb0 + j;
    if (wb >= nbins_chunk) break;
    float a0 = 0.f, a1 = 0.f;
    for (int p = b[j]; p < b[j + 1]; p++) {
      int2 rec = pairs[p];
      float w = __int_as_float(rec.y);
      if (C == 64) {
        a0 += w * b2f(Xb[(long)rec.x * 64 + lane]);
      } else {
        unsigned u = *(const unsigned*)(Xb + (long)rec.x * 128 + lane * 2);
        a0 += w * b2f((unsigned short)(u & 0xffffu));
        a1 += w * b2f((unsigned short)(u >> 16));
      }
    }
    if (C == 64) {
      accb[(long)wb * 64 + lane] = f2b(a0);
    } else {
      unsigned pk = (unsigned)f2b(a0) | ((unsigned)f2b(a1) << 16);
      *(unsigned*)(accb + (long)wb * 128 + lane * 2) = pk;
    }
  }
}

// ---------------- LDS-staged MFMA GEMM, 128 cols, K-extension for root GEMM ------
// A spline rows [M][KSP] from accb; for k0 >= KSP the staging switches to
// Aext [M][EC] (features) and Bext [NCOLS][EC] (root weight) -> root GEMM fused.
template<int NCOLS, int EC, bool ATOMIC>
__global__ __launch_bounds__(256, 2) void gemm_tile(
    const unsigned short* __restrict__ A, const unsigned short* __restrict__ Aext,
    const unsigned short* __restrict__ Bt, const unsigned short* __restrict__ Bext,
    float* __restrict__ C, int M, int KSP) {
  __shared__ unsigned short As[128 * 32];
  __shared__ unsigned short Bs[128 * 32];
  int wid = threadIdx.x >> 6, lane = threadIdx.x & 63;
  int row0 = blockIdx.x * 128;
  int Ktot = KSP + EC;
  int nslice = gridDim.y;
  int kslice = CDIV(Ktot / 32, nslice) * 32;
  int kbeg = blockIdx.y * kslice;
  int kend = kbeg + kslice; if (kend > Ktot) kend = Ktot;
  if (kbeg >= Ktot) return;

  int sub = lane & 3;
  int rload = lane >> 2;
  int q = lane >> 4, m16 = lane & 15;

  floatx4 acc[2][8];
#pragma unroll
  for (int t = 0; t < 2; t++)
#pragma unroll
    for (int c = 0; c < 8; c++) acc[t][c] = (floatx4){0.f, 0.f, 0.f, 0.f};

  for (int k0 = kbeg; k0 < kend; k0 += 32) {
    __syncthreads();
#pragma unroll
    for (int j = 0; j < 2; j++) {
      int tr = (wid * 2 + j) * 16 + rload;
      int gr = row0 + tr; if (gr >= M) gr = M - 1;
      const unsigned short* ap;
      const unsigned short* bp;
      if (k0 < KSP) {
        ap = A + (long)gr * KSP + k0 + sub * 8;
        bp = Bt + (long)tr * KSP + k0 + sub * 8;
      } else {
        ap = Aext + (long)gr * EC + (k0 - KSP) + sub * 8;
        bp = Bext + (long)tr * EC + (k0 - KSP) + sub * 8;
      }
      ld_g2l16(ap, As + (wid * 2 + j) * 512);
      ld_g2l16(bp, Bs + (wid * 2 + j) * 512);
    }
    __syncthreads();
#pragma unroll
    for (int t = 0; t < 2; t++) {
      int arow = wid * 32 + t * 16 + m16;
      short8 a = *(const short8*)(As + arow * 32 + q * 8);
#pragma unroll
      for (int c = 0; c < 8; c++) {
        short8 b = *(const short8*)(Bs + (c * 16 + m16) * 32 + q * 8);
        acc[t][c] = __builtin_amdgcn_mfma_f32_16x16x32_bf16(a, b, acc[t][c], 0, 0, 0);
      }
    }
  }

#pragma unroll
  for (int t = 0; t < 2; t++) {
#pragma unroll
    for (int c = 0; c < 8; c++) {
#pragma unroll
      for (int r = 0; r < 4; r++) {
        int orow = row0 + wid * 32 + t * 16 + q * 4 + r;
        if (orow < M) {
          float* p = &C[(long)orow * NCOLS + c * 16 + m16];
          if (ATOMIC) atomicAdd(p, acc[t][c][r]);
          else *p = acc[t][c][r];
        }
      }
    }
  }
}

// ---------------- 128x256 tile GEMM with K-extension (conv1+shortcut+roots) ------
template<int EC, bool ATOMIC>
__global__ __launch_bounds__(256, 2) void gemm_tile_w256(
    const unsigned short* __restrict__ A, const unsigned short* __restrict__ Aext,
    const unsigned short* __restrict__ Bt, const unsigned short* __restrict__ Bext,
    float* __restrict__ C, int M, int KSP) {
  __shared__ unsigned short As[128 * 32];
  __shared__ unsigned short Bs[256 * 32];
  int wid = threadIdx.x >> 6, lane = threadIdx.x & 63;
  int row0 = blockIdx.x * 128;
  int Ktot = KSP + EC;
  int nslice = gridDim.y;
  int kslice = CDIV(Ktot / 32, nslice) * 32;
  int kbeg = blockIdx.y * kslice;
  int kend = kbeg + kslice; if (kend > Ktot) kend = Ktot;
  if (kbeg >= Ktot) return;

  int sub = lane & 3;
  int rload = lane >> 2;
  int q = lane >> 4, m16 = lane & 15;

  floatx4 acc[2][16];
#pragma unroll
  for (int t = 0; t < 2; t++)
#pragma unroll
    for (int c = 0; c < 16; c++) acc[t][c] = (floatx4){0.f, 0.f, 0.f, 0.f};

  for (int k0 = kbeg; k0 < kend; k0 += 32) {
    __syncthreads();
    bool sp = (k0 < KSP);
    int ke = sp ? k0 : (k0 - KSP);
#pragma unroll
    for (int j = 0; j < 2; j++) {
      int tr = (wid * 2 + j) * 16 + rload;
      int gr = row0 + tr; if (gr >= M) gr = M - 1;
      const unsigned short* ap = sp ? (A + (long)gr * KSP + ke + sub * 8)
                                    : (Aext + (long)gr * EC + ke + sub * 8);
      ld_g2l16(ap, As + (wid * 2 + j) * 512);
    }
#pragma unroll
    for (int j = 0; j < 4; j++) {
      int tr = (wid * 4 + j) * 16 + rload;
      const unsigned short* bp = sp ? (Bt + (long)tr * KSP + ke + sub * 8)
                                    : (Bext + (long)tr * EC + ke + sub * 8);
      ld_g2l16(bp, Bs + (wid * 4 + j) * 512);
    }
    __syncthreads();
#pragma unroll
    for (int t = 0; t < 2; t++) {
      int arow = wid * 32 + t * 16 + m16;
      short8 a = *(const short8*)(As + arow * 32 + q * 8);
#pragma unroll
      for (int c = 0; c < 16; c++) {
        short8 b = *(const short8*)(Bs + (c * 16 + m16) * 32 + q * 8);
        acc[t][c] = __builtin_amdgcn_mfma_f32_16x16x32_bf16(a, b, acc[t][c], 0, 0, 0);
      }
    }
  }

#pragma unroll
  for (int t = 0; t < 2; t++) {
#pragma unroll
    for (int c = 0; c < 16; c++) {
#pragma unroll
      for (int r = 0; r < 4; r++) {
        int orow = row0 + wid * 32 + t * 16 + q * 4 + r;
        if (orow < M) {
          float* p = &C[(long)orow * 256 + c * 16 + m16];
          if (ATOMIC) atomicAdd(p, acc[t][c][r]);
          else *p = acc[t][c][r];
        }
      }
    }
  }
}

// ---------------- epilogues (root folded into GEMM; weights carry 1/deg) --------
__global__ void finalize_stats(const float* __restrict__ msgaug,
                               const float* __restrict__ bias,
                               float* __restrict__ out, float* __restrict__ stats, int n) {
  int c = threadIdx.x & 127;
  float bv = bias[c];
  float s = 0.f, s2 = 0.f;
  long tot = (long)n * COUT;
  long stride = (long)gridDim.x * 256;
  for (long i = (long)blockIdx.x * 256 + threadIdx.x; i < tot; i += stride) {
    int r = (int)(i >> 7);
    float v = msgaug[(long)r * 256 + c] + bv;
    out[i] = v;
    s += v; s2 += v * v;
  }
  __shared__ float ls[256], ls2[256];
  ls[threadIdx.x] = s; ls2[threadIdx.x] = s2;
  __syncthreads();
  if (threadIdx.x < 128) {
    atomicAdd(&stats[c], ls[threadIdx.x] + ls[threadIdx.x + 128]);
    atomicAdd(&stats[128 + c], ls2[threadIdx.x] + ls2[threadIdx.x + 128]);
  }
}

__global__ void finalize2_dual(const float* __restrict__ msg2, const float* __restrict__ b2,
                               const float* __restrict__ msgaug, const float* __restrict__ bsc,
                               float* __restrict__ h2r, float* __restrict__ sraw,
                               float* __restrict__ stats2, float* __restrict__ statssc, int n) {
  int c = threadIdx.x & 127;
  float bv2 = b2[c], bvsc = bsc[c];
  float sa = 0.f, sb = 0.f, ta = 0.f, tb = 0.f;
  long tot = (long)n * COUT;
  long stride = (long)gridDim.x * 256;
  for (long i = (long)blockIdx.x * 256 + threadIdx.x; i < tot; i += stride) {
    int r = (int)(i >> 7);
    float v2 = msg2[i] + bv2;
    h2r[i] = v2;
    sa += v2; sb += v2 * v2;
    float vs = msgaug[(long)r * 256 + 128 + c] + bvsc;
    sraw[i] = vs;
    ta += vs; tb += vs * vs;
  }
  __shared__ float l0[256], l1[256], l2[256], l3[256];
  l0[threadIdx.x] = sa; l1[threadIdx.x] = sb; l2[threadIdx.x] = ta; l3[threadIdx.x] = tb;
  __syncthreads();
  if (threadIdx.x < 128) {
    atomicAdd(&stats2[c], l0[threadIdx.x] + l0[threadIdx.x + 128]);
    atomicAdd(&stats2[128 + c], l1[threadIdx.x] + l1[threadIdx.x + 128]);
    atomicAdd(&statssc[c], l2[threadIdx.x] + l2[threadIdx.x + 128]);
    atomicAdd(&statssc[128 + c], l3[threadIdx.x] + l3[threadIdx.x + 128]);
  }
}

__global__ void bn_elu_kernel(float* __restrict__ h, unsigned short* __restrict__ hb,
                              const float* __restrict__ stats, const float* __restrict__ g,
                              const float* __restrict__ be, int n) {
  long i = (long)blockIdx.x * 256 + threadIdx.x;
  if (i >= (long)n * COUT) return;
  int c = (int)(i & 127);
  float inv_n = 1.0f / n;
  float mu = stats[c] * inv_n;
  float var = stats[128 + c] * inv_n - mu * mu;
  float v = (h[i] - mu) * rsqrtf(var + EPS) * g[c] + be[c];
  v = v > 0.f ? v : expm1f(v);
  h[i] = v;
  hb[i] = f2b(v);
}

__global__ void final_out_kernel(const float* __restrict__ h2, const float* __restrict__ sraw,
                                 const float* __restrict__ st2, const float* __restrict__ stsc,
                                 const float* __restrict__ g2, const float* __restrict__ be2,
                                 const float* __restrict__ gsc, const float* __restrict__ besc,
                                 float* __restrict__ out, int n) {
  long i = (long)blockIdx.x * 256 + threadIdx.x;
  if (i >= (long)n * COUT) return;
  int c = (int)(i & 127);
  float inv_n = 1.0f / n;
  float mu2 = st2[c] * inv_n;
  float var2 = st2[128 + c] * inv_n - mu2 * mu2;
  float a = (h2[i] - mu2) * rsqrtf(var2 + EPS) * g2[c] + be2[c];
  float musc = stsc[c] * inv_n;
  float varsc = stsc[128 + c] * inv_n - musc * musc;
  float b = (sraw[i] - musc) * rsqrtf(varsc + EPS) * gsc[c] + besc[c];
  float v = a + b;
  out[i] = v > 0.f ? v : expm1f(v);
}

// ---------------- host ----------------
extern "C" void kernel_launch(void* const* d_in, const int* in_sizes, int n_in,
                              void* d_out, int out_size, void* d_ws, size_t ws_size,
                              hipStream_t stream) {
  const float* x    = (const float*)d_in[0];
  const int*   eidx = (const int*)d_in[1];
  const float* attr = (const float*)d_in[2];
  const float* W1   = (const float*)d_in[3];
  const float* Wr1  = (const float*)d_in[4];
  const float* b1   = (const float*)d_in[5];
  const float* g1   = (const float*)d_in[6];
  const float* be1  = (const float*)d_in[7];
  const float* W2   = (const float*)d_in[8];
  const float* Wr2  = (const float*)d_in[9];
  const float* b2   = (const float*)d_in[10];
  const float* g2   = (const float*)d_in[11];
  const float* be2  = (const float*)d_in[12];
  const float* Wsc  = (const float*)d_in[13];
  const float* Wrsc = (const float*)d_in[14];
  const float* bsc  = (const float*)d_in[15];
  const float* gsc  = (const float*)d_in[16];
  const float* besc = (const float*)d_in[17];
  float* out = (float*)d_out;

  const int* src = eidx;
  const int* dst = eidx + N_EDGES;

  char* base = (char*)d_ws;
  size_t off = 0;
  auto alloc = [&](size_t bytes) -> char* {
    char* p = base + off;
    off += (bytes + 255) & ~(size_t)255;
    return p;
  };
  int* ecnt   = (int*)alloc((size_t)N_NODES * 4);
  int* erowptr= (int*)alloc((size_t)(N_NODES + 1) * 4);
  int* ecur   = (int*)alloc((size_t)N_NODES * 4);
  int* eorder = (int*)alloc((size_t)N_EDGES * 4);
  int* rowptr2= (int*)alloc((size_t)(NBINS + 1) * 4);
  int2* pairs = (int2*)alloc((size_t)NPAIRS * 8);
  unsigned short* xb    = (unsigned short*)alloc((size_t)N_NODES * CIN * 2);
  unsigned short* hb    = (unsigned short*)alloc((size_t)N_NODES * COUT * 2);
  unsigned short* W1aug = (unsigned short*)alloc((size_t)256 * KTOT * CIN * 2);
  unsigned short* W2t   = (unsigned short*)alloc((size_t)COUT * KTOT * COUT * 2);
  unsigned short* rootBt= (unsigned short*)alloc((size_t)256 * CIN * 2);
  unsigned short* Wr2t  = (unsigned short*)alloc((size_t)COUT * COUT * 2);
  float* msgaug= (float*)alloc((size_t)N_NODES * 256 * 4);    // conv1+shortcut (zeroed)
  float* msg2  = (float*)alloc((size_t)N_NODES * COUT * 4);   // conv2 (zeroed, adjacent)
  float* h1    = (float*)alloc((size_t)N_NODES * COUT * 4);
  float* h2r   = (float*)alloc((size_t)N_NODES * COUT * 4);
  float* sraw  = (float*)alloc((size_t)N_NODES * COUT * 4);
  float* stats = (float*)alloc(6 * 128 * 4);
  unsigned short* accb = (unsigned short*)(base + off);
  size_t avail = (ws_size > off) ? (ws_size - off) : 0;
  size_t per_node = (size_t)KTOT * COUT * 2;
  size_t chmax = avail / per_node;
  int CH = (int)((chmax < (size_t)N_NODES) ? chmax : (size_t)N_NODES);
  if (CH < 1) CH = 1;
  const int SPLIT = 10;

  hipMemsetAsync(ecnt, 0, (size_t)N_NODES * 4, stream);
  hipMemsetAsync(msgaug, 0, (size_t)N_NODES * (256 + 128) * 4, stream); // msgaug + msg2

  // edge CSR: dst-sorted edge permutation
  ecount<<<CDIV(N_EDGES, 256), 256, 0, stream>>>(dst, ecnt, N_EDGES);
  escan<<<1, 256, 0, stream>>>(ecnt, erowptr, ecur, N_NODES, rowptr2, stats);
  efill<<<CDIV(N_EDGES, 256), 256, 0, stream>>>(dst, ecur, eorder, N_EDGES);

  // per-node pair build (weights carry 1/deg)
  build_pairs<<<CDIV(N_NODES, 4), 256, 0, stream>>>(eorder, erowptr, src, attr,
                                                    rowptr2, pairs);

  const long CONV_TOT = 640000L + 1024000L + 2048000L + 8192 + 8192 + 16384 + 1024000L;
  convert_all<<<CDIV(CONV_TOT, 256), 256, 0, stream>>>(x, W1, W2, Wr1, Wrsc, Wr2, Wsc,
                                                       xb, W1aug, W2t, rootBt, Wr2t);

  // ---- conv1 + shortcut spline + both root GEMMs (K-extension) ----
  for (int c0 = 0; c0 < N_NODES; c0 += CH) {
    int cm = (N_NODES - c0 < CH) ? (N_NODES - c0) : CH;
    int nbc = cm * KTOT;
    scatter_bins<64><<<CDIV(nbc, 32), 256, 0, stream>>>(xb, rowptr2, pairs, accb,
                                                        c0 * KTOT, nbc);
    dim3 g(CDIV(cm, 128), SPLIT);
    gemm_tile_w256<64, true><<<g, 256, 0, stream>>>(
        accb, xb + (size_t)c0 * CIN, W1aug, rootBt,
        msgaug + (size_t)c0 * 256, cm, KTOT * CIN);
  }
  finalize_stats<<<64, 256, 0, stream>>>(msgaug, b1, h1, stats, N_NODES);
  bn_elu_kernel<<<CDIV(N_NODES * COUT, 256), 256, 0, stream>>>(h1, hb, stats, g1, be1, N_NODES);

  // ---- conv2 + root GEMM (K-extension) ----
  for (int c0 = 0; c0 < N_NODES; c0 += CH) {
    int cm = (N_NODES - c0 < CH) ? (N_NODES - c0) : CH;
    int nbc = cm * KTOT;
    scatter_bins<128><<<CDIV(nbc, 32), 256, 0, stream>>>(hb, rowptr2, pairs, accb,
                                                         c0 * KTOT, nbc);
    dim3 g(CDIV(cm, 128), SPLIT);
    gemm_tile<COUT, 128, true><<<g, 256, 0, stream>>>(
        accb, hb + (size_t)c0 * COUT, W2t, Wr2t,
        msg2 + (size_t)c0 * COUT, cm, KTOT * COUT);
  }
  finalize2_dual<<<64, 256, 0, stream>>>(msg2, b2, msgaug, bsc, h2r, sraw,
                                         stats + 256, stats + 512, N_NODES);

  // ---- output ----
  final_out_kernel<<<CDIV(N_NODES * COUT, 256), 256, 0, stream>>>(
      h2r, sraw, stats + 256, stats + 512, g2, be2, gsc, besc, out, N_NODES);
}

// Round 12
// 783.132 us; speedup vs baseline: 4.8142x; 1.0244x over previous
//
#include <hip/hip_runtime.h>

#define N_NODES 10000
#define N_EDGES 160000
#define CIN 64
#define COUT 128
#define KTOT 125
#define NBINS (N_NODES * KTOT)          // 1,250,000
#define NPAIRS (N_EDGES * 8)            // 1,280,000
#define EPS 1e-5f

#define CDIV(a,b) (((a)+(b)-1)/(b))

typedef __attribute__((ext_vector_type(8))) short short8;
typedef __attribute__((ext_vector_type(4))) float floatx4;

static __device__ __forceinline__ unsigned short f2b(float f) {
  union { float f; unsigned u; } v; v.f = f;
  unsigned r = v.u + 0x7FFFu + ((v.u >> 16) & 1u);
  return (unsigned short)(r >> 16);
}
static __device__ __forceinline__ float b2f(unsigned short u) {
  union { unsigned u; float f; } v; v.u = ((unsigned)u) << 16;
  return v.f;
}

typedef __attribute__((address_space(1))) const unsigned int guint;
typedef __attribute__((address_space(3))) unsigned int luint;
static __device__ __forceinline__ void ld_g2l16(const void* g, void* l) {
  __builtin_amdgcn_global_load_lds((guint*)g, (luint*)l, 16, 0, 0);
}

// ---------------- edge CSR (dst-sorted edge order) ----------
__global__ void ecount(const int* __restrict__ dst, int* __restrict__ ecnt, int E) {
  int e = blockIdx.x * 256 + threadIdx.x;
  if (e < E) atomicAdd(&ecnt[dst[e]], 1);
}

// single-block exclusive scan over n=10000; seeds ecur; zeroes stats; caps rowptr2
__global__ void escan(const int* __restrict__ cnt, int* __restrict__ rowptr,
                      int* __restrict__ cur, int n, int* __restrict__ rowptr2,
                      float* __restrict__ stats) {
  for (int i = threadIdx.x; i < 6 * 128; i += 256) stats[i] = 0.f;
  __shared__ int buf[256];
  __shared__ int carry;
  if (threadIdx.x == 0) { carry = 0; rowptr[0] = 0; rowptr2[NBINS] = NPAIRS; }
  __syncthreads();
  for (int base = 0; base < n; base += 256) {
    int i = base + threadIdx.x;
    int v = (i < n) ? cnt[i] : 0;
    buf[threadIdx.x] = v;
    __syncthreads();
    for (int s = 1; s < 256; s <<= 1) {
      int t = (threadIdx.x >= s) ? buf[threadIdx.x - s] : 0;
      __syncthreads();
      buf[threadIdx.x] += t;
      __syncthreads();
    }
    if (i < n) {
      int incl = carry + buf[threadIdx.x];
      rowptr[i + 1] = incl;
      cur[i] = incl - v;
    }
    __syncthreads();
    if (threadIdx.x == 255) carry += buf[255];
    __syncthreads();
  }
}

__global__ void efill(const int* __restrict__ dst, int* __restrict__ ecur,
                      int* __restrict__ eorder, int E) {
  int e = blockIdx.x * 256 + threadIdx.x;
  if (e >= E) return;
  int pos = atomicAdd(&ecur[dst[e]], 1);
  eorder[pos] = e;
}

// ---------------- build_pairs: one wave per node ----------------
__global__ __launch_bounds__(256) void build_pairs(
    const int* __restrict__ eorder, const int* __restrict__ erowptr,
    const int* __restrict__ src, const float* __restrict__ attr,
    int* __restrict__ rowptr2, int2* __restrict__ pairs) {
  __shared__ int hist_s[4][126];
  __shared__ int cur_s[4][126];
  int w = threadIdx.x >> 6, lane = threadIdx.x & 63;
  int node = blockIdx.x * 4 + w;
  if (node >= N_NODES) return;
  int* hist = hist_s[w];
  int* cur = cur_s[w];
  hist[lane] = 0;
  if (lane < 61) hist[64 + lane] = 0;
  __builtin_amdgcn_s_waitcnt(0);
  int e0 = erowptr[node], e1 = erowptr[node + 1];
  int deg = e1 - e0;
  float invdeg = 1.0f / fmaxf((float)deg, 1.0f);
  int sub_e = lane >> 3, corner = lane & 7;
  int bit0 = corner & 1, bit1 = (corner >> 1) & 1, bit2 = (corner >> 2) & 1;
  for (int base = 0; base < deg; base += 8) {
    int ei = base + sub_e;
    if (ei < deg) {
      int e = eorder[e0 + ei];
      float v0 = attr[e * 3 + 0] * 4.f;
      float v1 = attr[e * 3 + 1] * 4.f;
      float v2 = attr[e * 3 + 2] * 4.f;
      int i0 = (int)floorf(v0), i1 = (int)floorf(v1), i2 = (int)floorf(v2);
      int k0 = min(max(i0 + bit0, 0), 4);
      int k1 = min(max(i1 + bit1, 0), 4);
      int k2 = min(max(i2 + bit2, 0), 4);
      atomicAdd(&hist[k0 * 25 + k1 * 5 + k2], 1);
    }
  }
  __builtin_amdgcn_s_waitcnt(0);
  int v0 = hist[lane];
  int v1 = (lane < 61) ? hist[64 + lane] : 0;
  int s0 = v0;
#pragma unroll
  for (int d = 1; d < 64; d <<= 1) {
    int t = __shfl_up(s0, d, 64);
    if (lane >= d) s0 += t;
  }
  int excl0 = s0 - v0;
  int tot0 = __shfl(s0, 63, 64);
  int s1 = v1;
#pragma unroll
  for (int d = 1; d < 64; d <<= 1) {
    int t = __shfl_up(s1, d, 64);
    if (lane >= d) s1 += t;
  }
  int excl1 = s1 - v1 + tot0;
  int basep = e0 * 8;
  long rbase = (long)node * KTOT;
  rowptr2[rbase + lane] = basep + excl0;
  cur[lane] = basep + excl0;
  if (lane < 61) {
    rowptr2[rbase + 64 + lane] = basep + excl1;
    cur[64 + lane] = basep + excl1;
  }
  __builtin_amdgcn_s_waitcnt(0);
  for (int base = 0; base < deg; base += 8) {
    int ei = base + sub_e;
    if (ei < deg) {
      int e = eorder[e0 + ei];
      float v0f = attr[e * 3 + 0] * 4.f;
      float v1f = attr[e * 3 + 1] * 4.f;
      float v2f = attr[e * 3 + 2] * 4.f;
      float b0f = floorf(v0f), b1f = floorf(v1f), b2f_ = floorf(v2f);
      float f0 = v0f - b0f, f1 = v1f - b1f, f2 = v2f - b2f_;
      int i0 = (int)b0f, i1 = (int)b1f, i2 = (int)b2f_;
      float wv = (bit0 ? f0 : 1.f - f0) * (bit1 ? f1 : 1.f - f1) * (bit2 ? f2 : 1.f - f2);
      int k0 = min(max(i0 + bit0, 0), 4);
      int k1 = min(max(i1 + bit1, 0), 4);
      int k2 = min(max(i2 + bit2, 0), 4);
      int pos = atomicAdd(&cur[k0 * 25 + k1 * 5 + k2], 1);
      int2 rec; rec.x = src[e]; rec.y = __float_as_int(wv * invdeg);
      pairs[pos] = rec;
    }
  }
}

// ---------------- one-shot convert: xb + all weight transposes ----------------
__global__ void convert_all(const float* __restrict__ x, const float* __restrict__ W1,
                            const float* __restrict__ W2, const float* __restrict__ Wr1,
                            const float* __restrict__ Wrsc, const float* __restrict__ Wr2,
                            const float* __restrict__ Wsc,
                            unsigned short* __restrict__ xb, unsigned short* __restrict__ W1aug,
                            unsigned short* __restrict__ W2t, unsigned short* __restrict__ rootBt,
                            unsigned short* __restrict__ Wr2t) {
  long i = (long)blockIdx.x * 256 + threadIdx.x;
  const long n0 = 640000, n1 = n0 + 1024000, n2 = n1 + 2048000,
             n3 = n2 + 8192, n4 = n3 + 8192, n5 = n4 + 16384, n6 = n5 + 1024000;
  if (i < n0) {
    xb[i] = f2b(x[i]);
  } else if (i < n1) {
    long j = i - n0; int k = (int)(j >> 7), c = (int)(j & 127);
    W1aug[(long)c * 8000 + k] = f2b(W1[j]);
  } else if (i < n2) {
    long j = i - n1; int k = (int)(j >> 7), c = (int)(j & 127);
    W2t[(long)c * 16000 + k] = f2b(W2[j]);
  } else if (i < n3) {
    long j = i - n2; int k = (int)(j >> 7), c = (int)(j & 127);
    rootBt[c * 64 + k] = f2b(Wr1[j]);
  } else if (i < n4) {
    long j = i - n3; int k = (int)(j >> 7), c = (int)(j & 127);
    rootBt[(128 + c) * 64 + k] = f2b(Wrsc[j]);
  } else if (i < n5) {
    long j = i - n4; int k = (int)(j >> 7), c = (int)(j & 127);
    Wr2t[c * 128 + k] = f2b(Wr2[j]);
  } else if (i < n6) {
    long j = i - n5;
    int c = (int)(j / 8000), kk = (int)(j % 8000);
    W1aug[(long)(128 + c) * 8000 + kk] = f2b(Wsc[(kk & 63) * 128 + c]);
  }
}

// ---------------- scatter: one wave per 8 consecutive bins, register accumulate --
template<int C>
__global__ __launch_bounds__(256) void scatter_bins(
    const unsigned short* __restrict__ Xb, const int* __restrict__ rowptr2,
    const int2* __restrict__ pairs,
    unsigned short* __restrict__ accb, int bin0, int nbins_chunk) {
  int wb0 = (blockIdx.x * 4 + (threadIdx.x >> 6)) * 8;
  if (wb0 >= nbins_chunk) return;
  int lane = threadIdx.x & 63;
  int bin = bin0 + wb0;
  int bounds = 0;
  if (lane < 9) bounds = rowptr2[bin + lane];
  int b[9];
#pragma unroll
  for (int j = 0; j < 9; j++) b[j] = __shfl(bounds, j, 64);
#pragma unroll
  for (int j = 0; j < 8; j++) {
    int wb = wb0 + j;
    if (wb >= nbins_chunk) break;
    float a0 = 0.f, a1 = 0.f;
    for (int p = b[j]; p < b[j + 1]; p++) {
      int2 rec = pairs[p];
      float w = __int_as_float(rec.y);
      if (C == 64) {
        a0 += w * b2f(Xb[(long)rec.x * 64 + lane]);
      } else {
        unsigned u = *(const unsigned*)(Xb + (long)rec.x * 128 + lane * 2);
        a0 += w * b2f((unsigned short)(u & 0xffffu));
        a1 += w * b2f((unsigned short)(u >> 16));
      }
    }
    if (C == 64) {
      accb[(long)wb * 64 + lane] = f2b(a0);
    } else {
      unsigned pk = (unsigned)f2b(a0) | ((unsigned)f2b(a1) << 16);
      *(unsigned*)(accb + (long)wb * 128 + lane * 2) = pk;
    }
  }
}

// ---------------- LDS-staged MFMA GEMM, 128 cols, K-extension for root GEMM ------
template<int NCOLS, int EC, bool ATOMIC>
__global__ __launch_bounds__(256, 2) void gemm_tile(
    const unsigned short* __restrict__ A, const unsigned short* __restrict__ Aext,
    const unsigned short* __restrict__ Bt, const unsigned short* __restrict__ Bext,
    float* __restrict__ C, int M, int KSP) {
  __shared__ unsigned short As[128 * 32];
  __shared__ unsigned short Bs[128 * 32];
  int wid = threadIdx.x >> 6, lane = threadIdx.x & 63;
  int row0 = blockIdx.x * 128;
  int Ktot = KSP + EC;
  int nslice = gridDim.y;
  int kslice = CDIV(Ktot / 32, nslice) * 32;
  int kbeg = blockIdx.y * kslice;
  int kend = kbeg + kslice; if (kend > Ktot) kend = Ktot;
  if (kbeg >= Ktot) return;

  int sub = lane & 3;
  int rload = lane >> 2;
  int q = lane >> 4, m16 = lane & 15;

  floatx4 acc[2][8];
#pragma unroll
  for (int t = 0; t < 2; t++)
#pragma unroll
    for (int c = 0; c < 8; c++) acc[t][c] = (floatx4){0.f, 0.f, 0.f, 0.f};

  for (int k0 = kbeg; k0 < kend; k0 += 32) {
    __syncthreads();
#pragma unroll
    for (int j = 0; j < 2; j++) {
      int tr = (wid * 2 + j) * 16 + rload;
      int gr = row0 + tr; if (gr >= M) gr = M - 1;
      const unsigned short* ap;
      const unsigned short* bp;
      if (k0 < KSP) {
        ap = A + (long)gr * KSP + k0 + sub * 8;
        bp = Bt + (long)tr * KSP + k0 + sub * 8;
      } else {
        ap = Aext + (long)gr * EC + (k0 - KSP) + sub * 8;
        bp = Bext + (long)tr * EC + (k0 - KSP) + sub * 8;
      }
      ld_g2l16(ap, As + (wid * 2 + j) * 512);
      ld_g2l16(bp, Bs + (wid * 2 + j) * 512);
    }
    __syncthreads();
#pragma unroll
    for (int t = 0; t < 2; t++) {
      int arow = wid * 32 + t * 16 + m16;
      short8 a = *(const short8*)(As + arow * 32 + q * 8);
#pragma unroll
      for (int c = 0; c < 8; c++) {
        short8 b = *(const short8*)(Bs + (c * 16 + m16) * 32 + q * 8);
        acc[t][c] = __builtin_amdgcn_mfma_f32_16x16x32_bf16(a, b, acc[t][c], 0, 0, 0);
      }
    }
  }

#pragma unroll
  for (int t = 0; t < 2; t++) {
#pragma unroll
    for (int c = 0; c < 8; c++) {
#pragma unroll
      for (int r = 0; r < 4; r++) {
        int orow = row0 + wid * 32 + t * 16 + q * 4 + r;
        if (orow < M) {
          float* p = &C[(long)orow * NCOLS + c * 16 + m16];
          if (ATOMIC) atomicAdd(p, acc[t][c][r]);
          else *p = acc[t][c][r];
        }
      }
    }
  }
}

// ---------------- 128x256 tile GEMM with K-extension (conv1+shortcut+roots) ------
template<int EC, bool ATOMIC>
__global__ __launch_bounds__(256, 2) void gemm_tile_w256(
    const unsigned short* __restrict__ A, const unsigned short* __restrict__ Aext,
    const unsigned short* __restrict__ Bt, const unsigned short* __restrict__ Bext,
    float* __restrict__ C, int M, int KSP) {
  __shared__ unsigned short As[128 * 32];
  __shared__ unsigned short Bs[256 * 32];
  int wid = threadIdx.x >> 6, lane = threadIdx.x & 63;
  int row0 = blockIdx.x * 128;
  int Ktot = KSP + EC;
  int nslice = gridDim.y;
  int kslice = CDIV(Ktot / 32, nslice) * 32;
  int kbeg = blockIdx.y * kslice;
  int kend = kbeg + kslice; if (kend > Ktot) kend = Ktot;
  if (kbeg >= Ktot) return;

  int sub = lane & 3;
  int rload = lane >> 2;
  int q = lane >> 4, m16 = lane & 15;

  floatx4 acc[2][16];
#pragma unroll
  for (int t = 0; t < 2; t++)
#pragma unroll
    for (int c = 0; c < 16; c++) acc[t][c] = (floatx4){0.f, 0.f, 0.f, 0.f};

  for (int k0 = kbeg; k0 < kend; k0 += 32) {
    __syncthreads();
    bool sp = (k0 < KSP);
    int ke = sp ? k0 : (k0 - KSP);
#pragma unroll
    for (int j = 0; j < 2; j++) {
      int tr = (wid * 2 + j) * 16 + rload;
      int gr = row0 + tr; if (gr >= M) gr = M - 1;
      const unsigned short* ap = sp ? (A + (long)gr * KSP + ke + sub * 8)
                                    : (Aext + (long)gr * EC + ke + sub * 8);
      ld_g2l16(ap, As + (wid * 2 + j) * 512);
    }
#pragma unroll
    for (int j = 0; j < 4; j++) {
      int tr = (wid * 4 + j) * 16 + rload;
      const unsigned short* bp = sp ? (Bt + (long)tr * KSP + ke + sub * 8)
                                    : (Bext + (long)tr * EC + ke + sub * 8);
      ld_g2l16(bp, Bs + (wid * 4 + j) * 512);
    }
    __syncthreads();
#pragma unroll
    for (int t = 0; t < 2; t++) {
      int arow = wid * 32 + t * 16 + m16;
      short8 a = *(const short8*)(As + arow * 32 + q * 8);
#pragma unroll
      for (int c = 0; c < 16; c++) {
        short8 b = *(const short8*)(Bs + (c * 16 + m16) * 32 + q * 8);
        acc[t][c] = __builtin_amdgcn_mfma_f32_16x16x32_bf16(a, b, acc[t][c], 0, 0, 0);
      }
    }
  }

#pragma unroll
  for (int t = 0; t < 2; t++) {
#pragma unroll
    for (int c = 0; c < 16; c++) {
#pragma unroll
      for (int r = 0; r < 4; r++) {
        int orow = row0 + wid * 32 + t * 16 + q * 4 + r;
        if (orow < M) {
          float* p = &C[(long)orow * 256 + c * 16 + m16];
          if (ATOMIC) atomicAdd(p, acc[t][c][r]);
          else *p = acc[t][c][r];
        }
      }
    }
  }
}

// ---------------- epilogues (root folded into GEMM; weights carry 1/deg) --------
__global__ void finalize_stats(const float* __restrict__ msgaug,
                               const float* __restrict__ bias,
                               float* __restrict__ out, float* __restrict__ stats, int n) {
  int c = threadIdx.x & 127;
  float bv = bias[c];
  float s = 0.f, s2 = 0.f;
  long tot = (long)n * COUT;
  long stride = (long)gridDim.x * 256;
  for (long i = (long)blockIdx.x * 256 + threadIdx.x; i < tot; i += stride) {
    int r = (int)(i >> 7);
    float v = msgaug[(long)r * 256 + c] + bv;
    out[i] = v;
    s += v; s2 += v * v;
  }
  __shared__ float ls[256], ls2[256];
  ls[threadIdx.x] = s; ls2[threadIdx.x] = s2;
  __syncthreads();
  if (threadIdx.x < 128) {
    atomicAdd(&stats[c], ls[threadIdx.x] + ls[threadIdx.x + 128]);
    atomicAdd(&stats[128 + c], ls2[threadIdx.x] + ls2[threadIdx.x + 128]);
  }
}

__global__ void finalize2_dual(const float* __restrict__ msg2, const float* __restrict__ b2,
                               const float* __restrict__ msgaug, const float* __restrict__ bsc,
                               float* __restrict__ h2r, float* __restrict__ sraw,
                               float* __restrict__ stats2, float* __restrict__ statssc, int n) {
  int c = threadIdx.x & 127;
  float bv2 = b2[c], bvsc = bsc[c];
  float sa = 0.f, sb = 0.f, ta = 0.f, tb = 0.f;
  long tot = (long)n * COUT;
  long stride = (long)gridDim.x * 256;
  for (long i = (long)blockIdx.x * 256 + threadIdx.x; i < tot; i += stride) {
    int r = (int)(i >> 7);
    float v2 = msg2[i] + bv2;
    h2r[i] = v2;
    sa += v2; sb += v2 * v2;
    float vs = msgaug[(long)r * 256 + 128 + c] + bvsc;
    sraw[i] = vs;
    ta += vs; tb += vs * vs;
  }
  __shared__ float l0[256], l1[256], l2[256], l3[256];
  l0[threadIdx.x] = sa; l1[threadIdx.x] = sb; l2[threadIdx.x] = ta; l3[threadIdx.x] = tb;
  __syncthreads();
  if (threadIdx.x < 128) {
    atomicAdd(&stats2[c], l0[threadIdx.x] + l0[threadIdx.x + 128]);
    atomicAdd(&stats2[128 + c], l1[threadIdx.x] + l1[threadIdx.x + 128]);
    atomicAdd(&statssc[c], l2[threadIdx.x] + l2[threadIdx.x + 128]);
    atomicAdd(&statssc[128 + c], l3[threadIdx.x] + l3[threadIdx.x + 128]);
  }
}

__global__ void bn_elu_kernel(float* __restrict__ h, unsigned short* __restrict__ hb,
                              const float* __restrict__ stats, const float* __restrict__ g,
                              const float* __restrict__ be, int n) {
  long i = (long)blockIdx.x * 256 + threadIdx.x;
  if (i >= (long)n * COUT) return;
  int c = (int)(i & 127);
  float inv_n = 1.0f / n;
  float mu = stats[c] * inv_n;
  float var = stats[128 + c] * inv_n - mu * mu;
  float v = (h[i] - mu) * rsqrtf(var + EPS) * g[c] + be[c];
  v = v > 0.f ? v : expm1f(v);
  h[i] = v;
  hb[i] = f2b(v);
}

__global__ void final_out_kernel(const float* __restrict__ h2, const float* __restrict__ sraw,
                                 const float* __restrict__ st2, const float* __restrict__ stsc,
                                 const float* __restrict__ g2, const float* __restrict__ be2,
                                 const float* __restrict__ gsc, const float* __restrict__ besc,
                                 float* __restrict__ out, int n) {
  long i = (long)blockIdx.x * 256 + threadIdx.x;
  if (i >= (long)n * COUT) return;
  int c = (int)(i & 127);
  float inv_n = 1.0f / n;
  float mu2 = st2[c] * inv_n;
  float var2 = st2[128 + c] * inv_n - mu2 * mu2;
  float a = (h2[i] - mu2) * rsqrtf(var2 + EPS) * g2[c] + be2[c];
  float musc = stsc[c] * inv_n;
  float varsc = stsc[128 + c] * inv_n - musc * musc;
  float b = (sraw[i] - musc) * rsqrtf(varsc + EPS) * gsc[c] + besc[c];
  float v = a + b;
  out[i] = v > 0.f ? v : expm1f(v);
}

// ---------------- host ----------------
extern "C" void kernel_launch(void* const* d_in, const int* in_sizes, int n_in,
                              void* d_out, int out_size, void* d_ws, size_t ws_size,
                              hipStream_t stream) {
  const float* x    = (const float*)d_in[0];
  const int*   eidx = (const int*)d_in[1];
  const float* attr = (const float*)d_in[2];
  const float* W1   = (const float*)d_in[3];
  const float* Wr1  = (const float*)d_in[4];
  const float* b1   = (const float*)d_in[5];
  const float* g1   = (const float*)d_in[6];
  const float* be1  = (const float*)d_in[7];
  const float* W2   = (const float*)d_in[8];
  const float* Wr2  = (const float*)d_in[9];
  const float* b2   = (const float*)d_in[10];
  const float* g2   = (const float*)d_in[11];
  const float* be2  = (const float*)d_in[12];
  const float* Wsc  = (const float*)d_in[13];
  const float* Wrsc = (const float*)d_in[14];
  const float* bsc  = (const float*)d_in[15];
  const float* gsc  = (const float*)d_in[16];
  const float* besc = (const float*)d_in[17];
  float* out = (float*)d_out;

  const int* src = eidx;
  const int* dst = eidx + N_EDGES;

  char* base = (char*)d_ws;
  size_t off = 0;
  auto alloc = [&](size_t bytes) -> char* {
    char* p = base + off;
    off += (bytes + 255) & ~(size_t)255;
    return p;
  };
  int* ecnt   = (int*)alloc((size_t)N_NODES * 4);
  int* erowptr= (int*)alloc((size_t)(N_NODES + 1) * 4);
  int* ecur   = (int*)alloc((size_t)N_NODES * 4);
  int* eorder = (int*)alloc((size_t)N_EDGES * 4);
  int* rowptr2= (int*)alloc((size_t)(NBINS + 1) * 4);
  int2* pairs = (int2*)alloc((size_t)NPAIRS * 8);
  unsigned short* xb    = (unsigned short*)alloc((size_t)N_NODES * CIN * 2);
  unsigned short* hb    = (unsigned short*)alloc((size_t)N_NODES * COUT * 2);
  unsigned short* W1aug = (unsigned short*)alloc((size_t)256 * KTOT * CIN * 2);
  unsigned short* W2t   = (unsigned short*)alloc((size_t)COUT * KTOT * COUT * 2);
  unsigned short* rootBt= (unsigned short*)alloc((size_t)256 * CIN * 2);
  unsigned short* Wr2t  = (unsigned short*)alloc((size_t)COUT * COUT * 2);
  float* msgaug= (float*)alloc((size_t)N_NODES * 256 * 4);    // conv1+shortcut (zeroed)
  float* msg2  = (float*)alloc((size_t)N_NODES * COUT * 4);   // conv2 (zeroed, adjacent)
  float* h1    = (float*)alloc((size_t)N_NODES * COUT * 4);
  float* h2r   = (float*)alloc((size_t)N_NODES * COUT * 4);
  float* sraw  = (float*)alloc((size_t)N_NODES * COUT * 4);
  float* stats = (float*)alloc(6 * 128 * 4);
  unsigned short* accb = (unsigned short*)(base + off);
  (void)ws_size;
  const int SPLIT1 = 5;   // conv1: 79*5=395 blocks, half the atomic RMW of 10
  const int SPLIT2 = 10;  // conv2: 28*10=280 blocks per chunk
  const int CH2 = 3520;   // conv2 chunk: 3520*125*128*2 = 112.6 MB < 256 MB L3

  hipMemsetAsync(ecnt, 0, (size_t)N_NODES * 4, stream);
  hipMemsetAsync(msgaug, 0, (size_t)N_NODES * (256 + 128) * 4, stream); // msgaug + msg2

  // edge CSR: dst-sorted edge permutation
  ecount<<<CDIV(N_EDGES, 256), 256, 0, stream>>>(dst, ecnt, N_EDGES);
  escan<<<1, 256, 0, stream>>>(ecnt, erowptr, ecur, N_NODES, rowptr2, stats);
  efill<<<CDIV(N_EDGES, 256), 256, 0, stream>>>(dst, ecur, eorder, N_EDGES);

  // per-node pair build (weights carry 1/deg)
  build_pairs<<<CDIV(N_NODES, 4), 256, 0, stream>>>(eorder, erowptr, src, attr,
                                                    rowptr2, pairs);

  const long CONV_TOT = 640000L + 1024000L + 2048000L + 8192 + 8192 + 16384 + 1024000L;
  convert_all<<<CDIV(CONV_TOT, 256), 256, 0, stream>>>(x, W1, W2, Wr1, Wrsc, Wr2, Wsc,
                                                       xb, W1aug, W2t, rootBt, Wr2t);

  // ---- conv1 + shortcut spline + both root GEMMs (K-extension); accb1 160 MB
  // fits L3 whole, so no chunking; SPLIT=5 halves split-K atomic traffic. ----
  {
    scatter_bins<64><<<CDIV(NBINS, 32), 256, 0, stream>>>(xb, rowptr2, pairs, accb,
                                                          0, NBINS);
    dim3 g(CDIV(N_NODES, 128), SPLIT1);
    gemm_tile_w256<64, true><<<g, 256, 0, stream>>>(
        accb, xb, W1aug, rootBt, msgaug, N_NODES, KTOT * CIN);
  }
  finalize_stats<<<64, 256, 0, stream>>>(msgaug, b1, h1, stats, N_NODES);
  bn_elu_kernel<<<CDIV(N_NODES * COUT, 256), 256, 0, stream>>>(h1, hb, stats, g1, be1, N_NODES);

  // ---- conv2 + root GEMM (K-extension), chunked so accb chunk stays L3-resident
  for (int c0 = 0; c0 < N_NODES; c0 += CH2) {
    int cm = (N_NODES - c0 < CH2) ? (N_NODES - c0) : CH2;
    int nbc = cm * KTOT;
    scatter_bins<128><<<CDIV(nbc, 32), 256, 0, stream>>>(hb, rowptr2, pairs, accb,
                                                         c0 * KTOT, nbc);
    dim3 g(CDIV(cm, 128), SPLIT2);
    gemm_tile<COUT, 128, true><<<g, 256, 0, stream>>>(
        accb, hb + (size_t)c0 * COUT, W2t, Wr2t,
        msg2 + (size_t)c0 * COUT, cm, KTOT * COUT);
  }
  finalize2_dual<<<64, 256, 0, stream>>>(msg2, b2, msgaug, bsc, h2r, sraw,
                                         stats + 256, stats + 512, N_NODES);

  // ---- output ----
  final_out_kernel<<<CDIV(N_NODES * COUT, 256), 256, 0, stream>>>(
      h2r, sraw, stats + 256, stats + 512, g2, be2, gsc, besc, out, N_NODES);
}

// Round 13
// 746.401 us; speedup vs baseline: 5.0511x; 1.0492x over previous
//
#include <hip/hip_runtime.h>

#define N_NODES 10000
#define N_EDGES 160000
#define CIN 64
#define COUT 128
#define KTOT 125
#define NBINS (N_NODES * KTOT)          // 1,250,000
#define NPAIRS (N_EDGES * 8)            // 1,280,000
#define EPS 1e-5f

#define CDIV(a,b) (((a)+(b)-1)/(b))

typedef __attribute__((ext_vector_type(8))) short short8;
typedef __attribute__((ext_vector_type(4))) float floatx4;

static __device__ __forceinline__ unsigned short f2b(float f) {
  union { float f; unsigned u; } v; v.f = f;
  unsigned r = v.u + 0x7FFFu + ((v.u >> 16) & 1u);
  return (unsigned short)(r >> 16);
}
static __device__ __forceinline__ float b2f(unsigned short u) {
  union { unsigned u; float f; } v; v.u = ((unsigned)u) << 16;
  return v.f;
}

typedef __attribute__((address_space(1))) const unsigned int guint;
typedef __attribute__((address_space(3))) unsigned int luint;
static __device__ __forceinline__ void ld_g2l16(const void* g, void* l) {
  __builtin_amdgcn_global_load_lds((guint*)g, (luint*)l, 16, 0, 0);
}

// ---------------- edge CSR (dst-sorted edge order) ----------
__global__ void ecount(const int* __restrict__ dst, int* __restrict__ ecnt, int E) {
  int e = blockIdx.x * 256 + threadIdx.x;
  if (e < E) atomicAdd(&ecnt[dst[e]], 1);
}

// single-block exclusive scan over n=10000; seeds ecur; zeroes stats; caps rowptr2
__global__ void escan(const int* __restrict__ cnt, int* __restrict__ rowptr,
                      int* __restrict__ cur, int n, int* __restrict__ rowptr2,
                      float* __restrict__ stats) {
  for (int i = threadIdx.x; i < 6 * 128; i += 256) stats[i] = 0.f;
  __shared__ int buf[256];
  __shared__ int carry;
  if (threadIdx.x == 0) { carry = 0; rowptr[0] = 0; rowptr2[NBINS] = NPAIRS; }
  __syncthreads();
  for (int base = 0; base < n; base += 256) {
    int i = base + threadIdx.x;
    int v = (i < n) ? cnt[i] : 0;
    buf[threadIdx.x] = v;
    __syncthreads();
    for (int s = 1; s < 256; s <<= 1) {
      int t = (threadIdx.x >= s) ? buf[threadIdx.x - s] : 0;
      __syncthreads();
      buf[threadIdx.x] += t;
      __syncthreads();
    }
    if (i < n) {
      int incl = carry + buf[threadIdx.x];
      rowptr[i + 1] = incl;
      cur[i] = incl - v;
    }
    __syncthreads();
    if (threadIdx.x == 255) carry += buf[255];
    __syncthreads();
  }
}

__global__ void efill(const int* __restrict__ dst, int* __restrict__ ecur,
                      int* __restrict__ eorder, int E) {
  int e = blockIdx.x * 256 + threadIdx.x;
  if (e >= E) return;
  int pos = atomicAdd(&ecur[dst[e]], 1);
  eorder[pos] = e;
}

// ---------------- build_pairs: one wave per node ----------------
__global__ __launch_bounds__(256) void build_pairs(
    const int* __restrict__ eorder, const int* __restrict__ erowptr,
    const int* __restrict__ src, const float* __restrict__ attr,
    int* __restrict__ rowptr2, int2* __restrict__ pairs) {
  __shared__ int hist_s[4][126];
  __shared__ int cur_s[4][126];
  int w = threadIdx.x >> 6, lane = threadIdx.x & 63;
  int node = blockIdx.x * 4 + w;
  if (node >= N_NODES) return;
  int* hist = hist_s[w];
  int* cur = cur_s[w];
  hist[lane] = 0;
  if (lane < 61) hist[64 + lane] = 0;
  __builtin_amdgcn_s_waitcnt(0);
  int e0 = erowptr[node], e1 = erowptr[node + 1];
  int deg = e1 - e0;
  float invdeg = 1.0f / fmaxf((float)deg, 1.0f);
  int sub_e = lane >> 3, corner = lane & 7;
  int bit0 = corner & 1, bit1 = (corner >> 1) & 1, bit2 = (corner >> 2) & 1;
  for (int base = 0; base < deg; base += 8) {
    int ei = base + sub_e;
    if (ei < deg) {
      int e = eorder[e0 + ei];
      float v0 = attr[e * 3 + 0] * 4.f;
      float v1 = attr[e * 3 + 1] * 4.f;
      float v2 = attr[e * 3 + 2] * 4.f;
      int i0 = (int)floorf(v0), i1 = (int)floorf(v1), i2 = (int)floorf(v2);
      int k0 = min(max(i0 + bit0, 0), 4);
      int k1 = min(max(i1 + bit1, 0), 4);
      int k2 = min(max(i2 + bit2, 0), 4);
      atomicAdd(&hist[k0 * 25 + k1 * 5 + k2], 1);
    }
  }
  __builtin_amdgcn_s_waitcnt(0);
  int v0 = hist[lane];
  int v1 = (lane < 61) ? hist[64 + lane] : 0;
  int s0 = v0;
#pragma unroll
  for (int d = 1; d < 64; d <<= 1) {
    int t = __shfl_up(s0, d, 64);
    if (lane >= d) s0 += t;
  }
  int excl0 = s0 - v0;
  int tot0 = __shfl(s0, 63, 64);
  int s1 = v1;
#pragma unroll
  for (int d = 1; d < 64; d <<= 1) {
    int t = __shfl_up(s1, d, 64);
    if (lane >= d) s1 += t;
  }
  int excl1 = s1 - v1 + tot0;
  int basep = e0 * 8;
  long rbase = (long)node * KTOT;
  rowptr2[rbase + lane] = basep + excl0;
  cur[lane] = basep + excl0;
  if (lane < 61) {
    rowptr2[rbase + 64 + lane] = basep + excl1;
    cur[64 + lane] = basep + excl1;
  }
  __builtin_amdgcn_s_waitcnt(0);
  for (int base = 0; base < deg; base += 8) {
    int ei = base + sub_e;
    if (ei < deg) {
      int e = eorder[e0 + ei];
      float v0f = attr[e * 3 + 0] * 4.f;
      float v1f = attr[e * 3 + 1] * 4.f;
      float v2f = attr[e * 3 + 2] * 4.f;
      float b0f = floorf(v0f), b1f = floorf(v1f), b2f_ = floorf(v2f);
      float f0 = v0f - b0f, f1 = v1f - b1f, f2 = v2f - b2f_;
      int i0 = (int)b0f, i1 = (int)b1f, i2 = (int)b2f_;
      float wv = (bit0 ? f0 : 1.f - f0) * (bit1 ? f1 : 1.f - f1) * (bit2 ? f2 : 1.f - f2);
      int k0 = min(max(i0 + bit0, 0), 4);
      int k1 = min(max(i1 + bit1, 0), 4);
      int k2 = min(max(i2 + bit2, 0), 4);
      int pos = atomicAdd(&cur[k0 * 25 + k1 * 5 + k2], 1);
      int2 rec; rec.x = src[e]; rec.y = __float_as_int(wv * invdeg);
      pairs[pos] = rec;
    }
  }
}

// ---------------- one-shot convert: xb + all weight transposes ----------------
__global__ void convert_all(const float* __restrict__ x, const float* __restrict__ W1,
                            const float* __restrict__ W2, const float* __restrict__ Wr1,
                            const float* __restrict__ Wrsc, const float* __restrict__ Wr2,
                            const float* __restrict__ Wsc,
                            unsigned short* __restrict__ xb, unsigned short* __restrict__ W1aug,
                            unsigned short* __restrict__ W2t, unsigned short* __restrict__ rootBt,
                            unsigned short* __restrict__ Wr2t) {
  long i = (long)blockIdx.x * 256 + threadIdx.x;
  const long n0 = 640000, n1 = n0 + 1024000, n2 = n1 + 2048000,
             n3 = n2 + 8192, n4 = n3 + 8192, n5 = n4 + 16384, n6 = n5 + 1024000;
  if (i < n0) {
    xb[i] = f2b(x[i]);
  } else if (i < n1) {
    long j = i - n0; int k = (int)(j >> 7), c = (int)(j & 127);
    W1aug[(long)c * 8000 + k] = f2b(W1[j]);
  } else if (i < n2) {
    long j = i - n1; int k = (int)(j >> 7), c = (int)(j & 127);
    W2t[(long)c * 16000 + k] = f2b(W2[j]);
  } else if (i < n3) {
    long j = i - n2; int k = (int)(j >> 7), c = (int)(j & 127);
    rootBt[c * 64 + k] = f2b(Wr1[j]);
  } else if (i < n4) {
    long j = i - n3; int k = (int)(j >> 7), c = (int)(j & 127);
    rootBt[(128 + c) * 64 + k] = f2b(Wrsc[j]);
  } else if (i < n5) {
    long j = i - n4; int k = (int)(j >> 7), c = (int)(j & 127);
    Wr2t[c * 128 + k] = f2b(Wr2[j]);
  } else if (i < n6) {
    long j = i - n5;
    int c = (int)(j / 8000), kk = (int)(j % 8000);
    W1aug[(long)(128 + c) * 8000 + kk] = f2b(Wsc[(kk & 63) * 128 + c]);
  }
}

// ---------------- scatter: one wave per 8 bins, first-pair MLP fast path --------
// ~1.02 pairs/bin: issue all 8 bins' first-pair rec loads, then all 8 row loads
// as independent (overlapped) vmem ops; rare extra pairs in a serial cleanup.
template<int C>
__global__ __launch_bounds__(256) void scatter_bins(
    const unsigned short* __restrict__ Xb, const int* __restrict__ rowptr2,
    const int2* __restrict__ pairs,
    unsigned short* __restrict__ accb, int bin0, int nbins_chunk) {
  int wb0 = (blockIdx.x * 4 + (threadIdx.x >> 6)) * 8;
  if (wb0 >= nbins_chunk) return;
  int lane = threadIdx.x & 63;
  int bin = bin0 + wb0;
  int bounds = 0;
  if (lane < 9) bounds = rowptr2[bin + lane];
  int b[9];
#pragma unroll
  for (int j = 0; j < 9; j++) b[j] = __shfl(bounds, j, 64);

  int cnt[8];
  int2 rec[8];
#pragma unroll
  for (int j = 0; j < 8; j++) {
    cnt[j] = b[j + 1] - b[j];
    int idx = (cnt[j] > 0) ? b[j] : 0;        // OOB-safe clamp; masked below
    rec[j] = pairs[idx];                      // 8 independent 8B loads
  }
  float a0[8], a1[8];
#pragma unroll
  for (int j = 0; j < 8; j++) {
    float w = __int_as_float(rec[j].y);
    if (C == 64) {
      float v = b2f(Xb[(long)rec[j].x * 64 + lane]);   // 8 independent row loads
      a0[j] = (cnt[j] > 0) ? w * v : 0.f;
      a1[j] = 0.f;
    } else {
      unsigned u = *(const unsigned*)(Xb + (long)rec[j].x * 128 + lane * 2);
      float v0 = b2f((unsigned short)(u & 0xffffu));
      float v1 = b2f((unsigned short)(u >> 16));
      a0[j] = (cnt[j] > 0) ? w * v0 : 0.f;
      a1[j] = (cnt[j] > 0) ? w * v1 : 0.f;
    }
  }
  // rare extras (P(cnt>=2) ~ 0.25): serial cleanup
#pragma unroll
  for (int j = 0; j < 8; j++) {
    for (int p = b[j] + 1; p < b[j + 1]; p++) {
      int2 r = pairs[p];
      float w = __int_as_float(r.y);
      if (C == 64) {
        a0[j] += w * b2f(Xb[(long)r.x * 64 + lane]);
      } else {
        unsigned u = *(const unsigned*)(Xb + (long)r.x * 128 + lane * 2);
        a0[j] += w * b2f((unsigned short)(u & 0xffffu));
        a1[j] += w * b2f((unsigned short)(u >> 16));
      }
    }
  }
#pragma unroll
  for (int j = 0; j < 8; j++) {
    int wb = wb0 + j;
    if (wb >= nbins_chunk) break;
    if (C == 64) {
      accb[(long)wb * 64 + lane] = f2b(a0[j]);
    } else {
      unsigned pk = (unsigned)f2b(a0[j]) | ((unsigned)f2b(a1[j]) << 16);
      *(unsigned*)(accb + (long)wb * 128 + lane * 2) = pk;
    }
  }
}

// ---------------- LDS-staged MFMA GEMM, 128 cols, K-extension for root GEMM ------
template<int NCOLS, int EC, bool ATOMIC>
__global__ __launch_bounds__(256, 2) void gemm_tile(
    const unsigned short* __restrict__ A, const unsigned short* __restrict__ Aext,
    const unsigned short* __restrict__ Bt, const unsigned short* __restrict__ Bext,
    float* __restrict__ C, int M, int KSP) {
  __shared__ unsigned short As[128 * 32];
  __shared__ unsigned short Bs[128 * 32];
  int wid = threadIdx.x >> 6, lane = threadIdx.x & 63;
  int row0 = blockIdx.x * 128;
  int Ktot = KSP + EC;
  int nslice = gridDim.y;
  int kslice = CDIV(Ktot / 32, nslice) * 32;
  int kbeg = blockIdx.y * kslice;
  int kend = kbeg + kslice; if (kend > Ktot) kend = Ktot;
  if (kbeg >= Ktot) return;

  int sub = lane & 3;
  int rload = lane >> 2;
  int q = lane >> 4, m16 = lane & 15;

  floatx4 acc[2][8];
#pragma unroll
  for (int t = 0; t < 2; t++)
#pragma unroll
    for (int c = 0; c < 8; c++) acc[t][c] = (floatx4){0.f, 0.f, 0.f, 0.f};

  for (int k0 = kbeg; k0 < kend; k0 += 32) {
    __syncthreads();
#pragma unroll
    for (int j = 0; j < 2; j++) {
      int tr = (wid * 2 + j) * 16 + rload;
      int gr = row0 + tr; if (gr >= M) gr = M - 1;
      const unsigned short* ap;
      const unsigned short* bp;
      if (k0 < KSP) {
        ap = A + (long)gr * KSP + k0 + sub * 8;
        bp = Bt + (long)tr * KSP + k0 + sub * 8;
      } else {
        ap = Aext + (long)gr * EC + (k0 - KSP) + sub * 8;
        bp = Bext + (long)tr * EC + (k0 - KSP) + sub * 8;
      }
      ld_g2l16(ap, As + (wid * 2 + j) * 512);
      ld_g2l16(bp, Bs + (wid * 2 + j) * 512);
    }
    __syncthreads();
#pragma unroll
    for (int t = 0; t < 2; t++) {
      int arow = wid * 32 + t * 16 + m16;
      short8 a = *(const short8*)(As + arow * 32 + q * 8);
#pragma unroll
      for (int c = 0; c < 8; c++) {
        short8 b = *(const short8*)(Bs + (c * 16 + m16) * 32 + q * 8);
        acc[t][c] = __builtin_amdgcn_mfma_f32_16x16x32_bf16(a, b, acc[t][c], 0, 0, 0);
      }
    }
  }

#pragma unroll
  for (int t = 0; t < 2; t++) {
#pragma unroll
    for (int c = 0; c < 8; c++) {
#pragma unroll
      for (int r = 0; r < 4; r++) {
        int orow = row0 + wid * 32 + t * 16 + q * 4 + r;
        if (orow < M) {
          float* p = &C[(long)orow * NCOLS + c * 16 + m16];
          if (ATOMIC) atomicAdd(p, acc[t][c][r]);
          else *p = acc[t][c][r];
        }
      }
    }
  }
}

// ---------------- 128x256 tile GEMM with K-extension (conv1+shortcut+roots) ------
template<int EC, bool ATOMIC>
__global__ __launch_bounds__(256, 2) void gemm_tile_w256(
    const unsigned short* __restrict__ A, const unsigned short* __restrict__ Aext,
    const unsigned short* __restrict__ Bt, const unsigned short* __restrict__ Bext,
    float* __restrict__ C, int M, int KSP) {
  __shared__ unsigned short As[128 * 32];
  __shared__ unsigned short Bs[256 * 32];
  int wid = threadIdx.x >> 6, lane = threadIdx.x & 63;
  int row0 = blockIdx.x * 128;
  int Ktot = KSP + EC;
  int nslice = gridDim.y;
  int kslice = CDIV(Ktot / 32, nslice) * 32;
  int kbeg = blockIdx.y * kslice;
  int kend = kbeg + kslice; if (kend > Ktot) kend = Ktot;
  if (kbeg >= Ktot) return;

  int sub = lane & 3;
  int rload = lane >> 2;
  int q = lane >> 4, m16 = lane & 15;

  floatx4 acc[2][16];
#pragma unroll
  for (int t = 0; t < 2; t++)
#pragma unroll
    for (int c = 0; c < 16; c++) acc[t][c] = (floatx4){0.f, 0.f, 0.f, 0.f};

  for (int k0 = kbeg; k0 < kend; k0 += 32) {
    __syncthreads();
    bool sp = (k0 < KSP);
    int ke = sp ? k0 : (k0 - KSP);
#pragma unroll
    for (int j = 0; j < 2; j++) {
      int tr = (wid * 2 + j) * 16 + rload;
      int gr = row0 + tr; if (gr >= M) gr = M - 1;
      const unsigned short* ap = sp ? (A + (long)gr * KSP + ke + sub * 8)
                                    : (Aext + (long)gr * EC + ke + sub * 8);
      ld_g2l16(ap, As + (wid * 2 + j) * 512);
    }
#pragma unroll
    for (int j = 0; j < 4; j++) {
      int tr = (wid * 4 + j) * 16 + rload;
      const unsigned short* bp = sp ? (Bt + (long)tr * KSP + ke + sub * 8)
                                    : (Bext + (long)tr * EC + ke + sub * 8);
      ld_g2l16(bp, Bs + (wid * 4 + j) * 512);
    }
    __syncthreads();
#pragma unroll
    for (int t = 0; t < 2; t++) {
      int arow = wid * 32 + t * 16 + m16;
      short8 a = *(const short8*)(As + arow * 32 + q * 8);
#pragma unroll
      for (int c = 0; c < 16; c++) {
        short8 b = *(const short8*)(Bs + (c * 16 + m16) * 32 + q * 8);
        acc[t][c] = __builtin_amdgcn_mfma_f32_16x16x32_bf16(a, b, acc[t][c], 0, 0, 0);
      }
    }
  }

#pragma unroll
  for (int t = 0; t < 2; t++) {
#pragma unroll
    for (int c = 0; c < 16; c++) {
#pragma unroll
      for (int r = 0; r < 4; r++) {
        int orow = row0 + wid * 32 + t * 16 + q * 4 + r;
        if (orow < M) {
          float* p = &C[(long)orow * 256 + c * 16 + m16];
          if (ATOMIC) atomicAdd(p, acc[t][c][r]);
          else *p = acc[t][c][r];
        }
      }
    }
  }
}

// ---------------- epilogues (root folded into GEMM; weights carry 1/deg) --------
__global__ void finalize_stats(const float* __restrict__ msgaug,
                               const float* __restrict__ bias,
                               float* __restrict__ out, float* __restrict__ stats, int n) {
  int c = threadIdx.x & 127;
  float bv = bias[c];
  float s = 0.f, s2 = 0.f;
  long tot = (long)n * COUT;
  long stride = (long)gridDim.x * 256;
  for (long i = (long)blockIdx.x * 256 + threadIdx.x; i < tot; i += stride) {
    int r = (int)(i >> 7);
    float v = msgaug[(long)r * 256 + c] + bv;
    out[i] = v;
    s += v; s2 += v * v;
  }
  __shared__ float ls[256], ls2[256];
  ls[threadIdx.x] = s; ls2[threadIdx.x] = s2;
  __syncthreads();
  if (threadIdx.x < 128) {
    atomicAdd(&stats[c], ls[threadIdx.x] + ls[threadIdx.x + 128]);
    atomicAdd(&stats[128 + c], ls2[threadIdx.x] + ls2[threadIdx.x + 128]);
  }
}

__global__ void finalize2_dual(const float* __restrict__ msg2, const float* __restrict__ b2,
                               const float* __restrict__ msgaug, const float* __restrict__ bsc,
                               float* __restrict__ h2r, float* __restrict__ sraw,
                               float* __restrict__ stats2, float* __restrict__ statssc, int n) {
  int c = threadIdx.x & 127;
  float bv2 = b2[c], bvsc = bsc[c];
  float sa = 0.f, sb = 0.f, ta = 0.f, tb = 0.f;
  long tot = (long)n * COUT;
  long stride = (long)gridDim.x * 256;
  for (long i = (long)blockIdx.x * 256 + threadIdx.x; i < tot; i += stride) {
    int r = (int)(i >> 7);
    float v2 = msg2[i] + bv2;
    h2r[i] = v2;
    sa += v2; sb += v2 * v2;
    float vs = msgaug[(long)r * 256 + 128 + c] + bvsc;
    sraw[i] = vs;
    ta += vs; tb += vs * vs;
  }
  __shared__ float l0[256], l1[256], l2[256], l3[256];
  l0[threadIdx.x] = sa; l1[threadIdx.x] = sb; l2[threadIdx.x] = ta; l3[threadIdx.x] = tb;
  __syncthreads();
  if (threadIdx.x < 128) {
    atomicAdd(&stats2[c], l0[threadIdx.x] + l0[threadIdx.x + 128]);
    atomicAdd(&stats2[128 + c], l1[threadIdx.x] + l1[threadIdx.x + 128]);
    atomicAdd(&statssc[c], l2[threadIdx.x] + l2[threadIdx.x + 128]);
    atomicAdd(&statssc[128 + c], l3[threadIdx.x] + l3[threadIdx.x + 128]);
  }
}

__global__ void bn_elu_kernel(float* __restrict__ h, unsigned short* __restrict__ hb,
                              const float* __restrict__ stats, const float* __restrict__ g,
                              const float* __restrict__ be, int n) {
  long i = (long)blockIdx.x * 256 + threadIdx.x;
  if (i >= (long)n * COUT) return;
  int c = (int)(i & 127);
  float inv_n = 1.0f / n;
  float mu = stats[c] * inv_n;
  float var = stats[128 + c] * inv_n - mu * mu;
  float v = (h[i] - mu) * rsqrtf(var + EPS) * g[c] + be[c];
  v = v > 0.f ? v : expm1f(v);
  h[i] = v;
  hb[i] = f2b(v);
}

__global__ void final_out_kernel(const float* __restrict__ h2, const float* __restrict__ sraw,
                                 const float* __restrict__ st2, const float* __restrict__ stsc,
                                 const float* __restrict__ g2, const float* __restrict__ be2,
                                 const float* __restrict__ gsc, const float* __restrict__ besc,
                                 float* __restrict__ out, int n) {
  long i = (long)blockIdx.x * 256 + threadIdx.x;
  if (i >= (long)n * COUT) return;
  int c = (int)(i & 127);
  float inv_n = 1.0f / n;
  float mu2 = st2[c] * inv_n;
  float var2 = st2[128 + c] * inv_n - mu2 * mu2;
  float a = (h2[i] - mu2) * rsqrtf(var2 + EPS) * g2[c] + be2[c];
  float musc = stsc[c] * inv_n;
  float varsc = stsc[128 + c] * inv_n - musc * musc;
  float b = (sraw[i] - musc) * rsqrtf(varsc + EPS) * gsc[c] + besc[c];
  float v = a + b;
  out[i] = v > 0.f ? v : expm1f(v);
}

// ---------------- host ----------------
extern "C" void kernel_launch(void* const* d_in, const int* in_sizes, int n_in,
                              void* d_out, int out_size, void* d_ws, size_t ws_size,
                              hipStream_t stream) {
  const float* x    = (const float*)d_in[0];
  const int*   eidx = (const int*)d_in[1];
  const float* attr = (const float*)d_in[2];
  const float* W1   = (const float*)d_in[3];
  const float* Wr1  = (const float*)d_in[4];
  const float* b1   = (const float*)d_in[5];
  const float* g1   = (const float*)d_in[6];
  const float* be1  = (const float*)d_in[7];
  const float* W2   = (const float*)d_in[8];
  const float* Wr2  = (const float*)d_in[9];
  const float* b2   = (const float*)d_in[10];
  const float* g2   = (const float*)d_in[11];
  const float* be2  = (const float*)d_in[12];
  const float* Wsc  = (const float*)d_in[13];
  const float* Wrsc = (const float*)d_in[14];
  const float* bsc  = (const float*)d_in[15];
  const float* gsc  = (const float*)d_in[16];
  const float* besc = (const float*)d_in[17];
  float* out = (float*)d_out;

  const int* src = eidx;
  const int* dst = eidx + N_EDGES;

  char* base = (char*)d_ws;
  size_t off = 0;
  auto alloc = [&](size_t bytes) -> char* {
    char* p = base + off;
    off += (bytes + 255) & ~(size_t)255;
    return p;
  };
  int* ecnt   = (int*)alloc((size_t)N_NODES * 4);
  int* erowptr= (int*)alloc((size_t)(N_NODES + 1) * 4);
  int* ecur   = (int*)alloc((size_t)N_NODES * 4);
  int* eorder = (int*)alloc((size_t)N_EDGES * 4);
  int* rowptr2= (int*)alloc((size_t)(NBINS + 1) * 4);
  int2* pairs = (int2*)alloc((size_t)NPAIRS * 8);
  unsigned short* xb    = (unsigned short*)alloc((size_t)N_NODES * CIN * 2);
  unsigned short* hb    = (unsigned short*)alloc((size_t)N_NODES * COUT * 2);
  unsigned short* W1aug = (unsigned short*)alloc((size_t)256 * KTOT * CIN * 2);
  unsigned short* W2t   = (unsigned short*)alloc((size_t)COUT * KTOT * COUT * 2);
  unsigned short* rootBt= (unsigned short*)alloc((size_t)256 * CIN * 2);
  unsigned short* Wr2t  = (unsigned short*)alloc((size_t)COUT * COUT * 2);
  float* msgaug= (float*)alloc((size_t)N_NODES * 256 * 4);    // conv1+shortcut (zeroed)
  float* msg2  = (float*)alloc((size_t)N_NODES * COUT * 4);   // conv2 (zeroed, adjacent)
  float* h1    = (float*)alloc((size_t)N_NODES * COUT * 4);
  float* h2r   = (float*)alloc((size_t)N_NODES * COUT * 4);
  float* sraw  = (float*)alloc((size_t)N_NODES * COUT * 4);
  float* stats = (float*)alloc(6 * 128 * 4);
  unsigned short* accb = (unsigned short*)(base + off);
  (void)ws_size;
  const int SPLIT1 = 5;   // conv1: 79*5=395 blocks
  const int SPLIT2 = 10;  // conv2: 28*10=280 blocks per chunk
  const int CH2 = 3520;   // conv2 chunk: 112.6 MB < 256 MB L3

  hipMemsetAsync(ecnt, 0, (size_t)N_NODES * 4, stream);
  hipMemsetAsync(msgaug, 0, (size_t)N_NODES * (256 + 128) * 4, stream); // msgaug + msg2

  // edge CSR: dst-sorted edge permutation
  ecount<<<CDIV(N_EDGES, 256), 256, 0, stream>>>(dst, ecnt, N_EDGES);
  escan<<<1, 256, 0, stream>>>(ecnt, erowptr, ecur, N_NODES, rowptr2, stats);
  efill<<<CDIV(N_EDGES, 256), 256, 0, stream>>>(dst, ecur, eorder, N_EDGES);

  // per-node pair build (weights carry 1/deg)
  build_pairs<<<CDIV(N_NODES, 4), 256, 0, stream>>>(eorder, erowptr, src, attr,
                                                    rowptr2, pairs);

  const long CONV_TOT = 640000L + 1024000L + 2048000L + 8192 + 8192 + 16384 + 1024000L;
  convert_all<<<CDIV(CONV_TOT, 256), 256, 0, stream>>>(x, W1, W2, Wr1, Wrsc, Wr2, Wsc,
                                                       xb, W1aug, W2t, rootBt, Wr2t);

  // ---- conv1 + shortcut spline + both root GEMMs (K-extension) ----
  {
    scatter_bins<64><<<CDIV(NBINS, 32), 256, 0, stream>>>(xb, rowptr2, pairs, accb,
                                                          0, NBINS);
    dim3 g(CDIV(N_NODES, 128), SPLIT1);
    gemm_tile_w256<64, true><<<g, 256, 0, stream>>>(
        accb, xb, W1aug, rootBt, msgaug, N_NODES, KTOT * CIN);
  }
  finalize_stats<<<64, 256, 0, stream>>>(msgaug, b1, h1, stats, N_NODES);
  bn_elu_kernel<<<CDIV(N_NODES * COUT, 256), 256, 0, stream>>>(h1, hb, stats, g1, be1, N_NODES);

  // ---- conv2 + root GEMM (K-extension), chunked so accb chunk stays L3-resident
  for (int c0 = 0; c0 < N_NODES; c0 += CH2) {
    int cm = (N_NODES - c0 < CH2) ? (N_NODES - c0) : CH2;
    int nbc = cm * KTOT;
    scatter_bins<128><<<CDIV(nbc, 32), 256, 0, stream>>>(hb, rowptr2, pairs, accb,
                                                         c0 * KTOT, nbc);
    dim3 g(CDIV(cm, 128), SPLIT2);
    gemm_tile<COUT, 128, true><<<g, 256, 0, stream>>>(
        accb, hb + (size_t)c0 * COUT, W2t, Wr2t,
        msg2 + (size_t)c0 * COUT, cm, KTOT * COUT);
  }
  finalize2_dual<<<64, 256, 0, stream>>>(msg2, b2, msgaug, bsc, h2r, sraw,
                                         stats + 256, stats + 512, N_NODES);

  // ---- output ----
  final_out_kernel<<<CDIV(N_NODES * COUT, 256), 256, 0, stream>>>(
      h2r, sraw, stats + 256, stats + 512, g2, be2, gsc, besc, out, N_NODES);
}

// Round 14
// 745.881 us; speedup vs baseline: 5.0546x; 1.0007x over previous
//
#include <hip/hip_runtime.h>

#define N_NODES 10000
#define N_EDGES 160000
#define CIN 64
#define COUT 128
#define KTOT 125
#define NBINS (N_NODES * KTOT)          // 1,250,000
#define NPAIRS (N_EDGES * 8)            // 1,280,000
#define EPS 1e-5f

#define CDIV(a,b) (((a)+(b)-1)/(b))

typedef __attribute__((ext_vector_type(8))) short short8;
typedef __attribute__((ext_vector_type(4))) float floatx4;

static __device__ __forceinline__ unsigned short f2b(float f) {
  union { float f; unsigned u; } v; v.f = f;
  unsigned r = v.u + 0x7FFFu + ((v.u >> 16) & 1u);
  return (unsigned short)(r >> 16);
}
static __device__ __forceinline__ float b2f(unsigned short u) {
  union { unsigned u; float f; } v; v.u = ((unsigned)u) << 16;
  return v.f;
}

typedef __attribute__((address_space(1))) const unsigned int guint;
typedef __attribute__((address_space(3))) unsigned int luint;
static __device__ __forceinline__ void ld_g2l16(const void* g, void* l) {
  __builtin_amdgcn_global_load_lds((guint*)g, (luint*)l, 16, 0, 0);
}

// ---------------- edge CSR (dst-sorted edge order) ----------
__global__ void ecount(const int* __restrict__ dst, int* __restrict__ ecnt, int E) {
  int e = blockIdx.x * 256 + threadIdx.x;
  if (e < E) atomicAdd(&ecnt[dst[e]], 1);
}

// single-block exclusive scan over n=10000; seeds ecur; zeroes stats; caps rowptr2
__global__ void escan(const int* __restrict__ cnt, int* __restrict__ rowptr,
                      int* __restrict__ cur, int n, int* __restrict__ rowptr2,
                      float* __restrict__ stats) {
  for (int i = threadIdx.x; i < 6 * 128; i += 256) stats[i] = 0.f;
  __shared__ int buf[256];
  __shared__ int carry;
  if (threadIdx.x == 0) { carry = 0; rowptr[0] = 0; rowptr2[NBINS] = NPAIRS; }
  __syncthreads();
  for (int base = 0; base < n; base += 256) {
    int i = base + threadIdx.x;
    int v = (i < n) ? cnt[i] : 0;
    buf[threadIdx.x] = v;
    __syncthreads();
    for (int s = 1; s < 256; s <<= 1) {
      int t = (threadIdx.x >= s) ? buf[threadIdx.x - s] : 0;
      __syncthreads();
      buf[threadIdx.x] += t;
      __syncthreads();
    }
    if (i < n) {
      int incl = carry + buf[threadIdx.x];
      rowptr[i + 1] = incl;
      cur[i] = incl - v;
    }
    __syncthreads();
    if (threadIdx.x == 255) carry += buf[255];
    __syncthreads();
  }
}

__global__ void efill(const int* __restrict__ dst, int* __restrict__ ecur,
                      int* __restrict__ eorder, int E) {
  int e = blockIdx.x * 256 + threadIdx.x;
  if (e >= E) return;
  int pos = atomicAdd(&ecur[dst[e]], 1);
  eorder[pos] = e;
}

// ---------------- build_pairs: one wave per node ----------------
__global__ __launch_bounds__(256) void build_pairs(
    const int* __restrict__ eorder, const int* __restrict__ erowptr,
    const int* __restrict__ src, const float* __restrict__ attr,
    int* __restrict__ rowptr2, int2* __restrict__ pairs) {
  __shared__ int hist_s[4][126];
  __shared__ int cur_s[4][126];
  int w = threadIdx.x >> 6, lane = threadIdx.x & 63;
  int node = blockIdx.x * 4 + w;
  if (node >= N_NODES) return;
  int* hist = hist_s[w];
  int* cur = cur_s[w];
  hist[lane] = 0;
  if (lane < 61) hist[64 + lane] = 0;
  __builtin_amdgcn_s_waitcnt(0);
  int e0 = erowptr[node], e1 = erowptr[node + 1];
  int deg = e1 - e0;
  float invdeg = 1.0f / fmaxf((float)deg, 1.0f);
  int sub_e = lane >> 3, corner = lane & 7;
  int bit0 = corner & 1, bit1 = (corner >> 1) & 1, bit2 = (corner >> 2) & 1;
  for (int base = 0; base < deg; base += 8) {
    int ei = base + sub_e;
    if (ei < deg) {
      int e = eorder[e0 + ei];
      float v0 = attr[e * 3 + 0] * 4.f;
      float v1 = attr[e * 3 + 1] * 4.f;
      float v2 = attr[e * 3 + 2] * 4.f;
      int i0 = (int)floorf(v0), i1 = (int)floorf(v1), i2 = (int)floorf(v2);
      int k0 = min(max(i0 + bit0, 0), 4);
      int k1 = min(max(i1 + bit1, 0), 4);
      int k2 = min(max(i2 + bit2, 0), 4);
      atomicAdd(&hist[k0 * 25 + k1 * 5 + k2], 1);
    }
  }
  __builtin_amdgcn_s_waitcnt(0);
  int v0 = hist[lane];
  int v1 = (lane < 61) ? hist[64 + lane] : 0;
  int s0 = v0;
#pragma unroll
  for (int d = 1; d < 64; d <<= 1) {
    int t = __shfl_up(s0, d, 64);
    if (lane >= d) s0 += t;
  }
  int excl0 = s0 - v0;
  int tot0 = __shfl(s0, 63, 64);
  int s1 = v1;
#pragma unroll
  for (int d = 1; d < 64; d <<= 1) {
    int t = __shfl_up(s1, d, 64);
    if (lane >= d) s1 += t;
  }
  int excl1 = s1 - v1 + tot0;
  int basep = e0 * 8;
  long rbase = (long)node * KTOT;
  rowptr2[rbase + lane] = basep + excl0;
  cur[lane] = basep + excl0;
  if (lane < 61) {
    rowptr2[rbase + 64 + lane] = basep + excl1;
    cur[64 + lane] = basep + excl1;
  }
  __builtin_amdgcn_s_waitcnt(0);
  for (int base = 0; base < deg; base += 8) {
    int ei = base + sub_e;
    if (ei < deg) {
      int e = eorder[e0 + ei];
      float v0f = attr[e * 3 + 0] * 4.f;
      float v1f = attr[e * 3 + 1] * 4.f;
      float v2f = attr[e * 3 + 2] * 4.f;
      float b0f = floorf(v0f), b1f = floorf(v1f), b2f_ = floorf(v2f);
      float f0 = v0f - b0f, f1 = v1f - b1f, f2 = v2f - b2f_;
      int i0 = (int)b0f, i1 = (int)b1f, i2 = (int)b2f_;
      float wv = (bit0 ? f0 : 1.f - f0) * (bit1 ? f1 : 1.f - f1) * (bit2 ? f2 : 1.f - f2);
      int k0 = min(max(i0 + bit0, 0), 4);
      int k1 = min(max(i1 + bit1, 0), 4);
      int k2 = min(max(i2 + bit2, 0), 4);
      int pos = atomicAdd(&cur[k0 * 25 + k1 * 5 + k2], 1);
      int2 rec; rec.x = src[e]; rec.y = __float_as_int(wv * invdeg);
      pairs[pos] = rec;
    }
  }
}

// ---------------- one-shot convert: xb + all weight transposes ----------------
__global__ void convert_all(const float* __restrict__ x, const float* __restrict__ W1,
                            const float* __restrict__ W2, const float* __restrict__ Wr1,
                            const float* __restrict__ Wrsc, const float* __restrict__ Wr2,
                            const float* __restrict__ Wsc,
                            unsigned short* __restrict__ xb, unsigned short* __restrict__ W1aug,
                            unsigned short* __restrict__ W2t, unsigned short* __restrict__ rootBt,
                            unsigned short* __restrict__ Wr2t) {
  long i = (long)blockIdx.x * 256 + threadIdx.x;
  const long n0 = 640000, n1 = n0 + 1024000, n2 = n1 + 2048000,
             n3 = n2 + 8192, n4 = n3 + 8192, n5 = n4 + 16384, n6 = n5 + 1024000;
  if (i < n0) {
    xb[i] = f2b(x[i]);
  } else if (i < n1) {
    long j = i - n0; int k = (int)(j >> 7), c = (int)(j & 127);
    W1aug[(long)c * 8000 + k] = f2b(W1[j]);
  } else if (i < n2) {
    long j = i - n1; int k = (int)(j >> 7), c = (int)(j & 127);
    W2t[(long)c * 16000 + k] = f2b(W2[j]);
  } else if (i < n3) {
    long j = i - n2; int k = (int)(j >> 7), c = (int)(j & 127);
    rootBt[c * 64 + k] = f2b(Wr1[j]);
  } else if (i < n4) {
    long j = i - n3; int k = (int)(j >> 7), c = (int)(j & 127);
    rootBt[(128 + c) * 64 + k] = f2b(Wrsc[j]);
  } else if (i < n5) {
    long j = i - n4; int k = (int)(j >> 7), c = (int)(j & 127);
    Wr2t[c * 128 + k] = f2b(Wr2[j]);
  } else if (i < n6) {
    long j = i - n5;
    int c = (int)(j / 8000), kk = (int)(j % 8000);
    W1aug[(long)(128 + c) * 8000 + kk] = f2b(Wsc[(kk & 63) * 128 + c]);
  }
}

// ---------------- scatter: 2 bins per wave-instruction ----------------
// Lanes 0-31 own bin 2j, lanes 32-63 own bin 2j+1; each lane covers 2 (C=64,
// u32) or 4 (C=128, u64) channels -> 256B per wave memory instruction, halving
// the issue count vs 1-bin-per-instr. First-pair loads stay independent (MLP);
// rare extra pairs handled in a divergent cleanup loop.
template<int C>
__global__ __launch_bounds__(256) void scatter_bins(
    const unsigned short* __restrict__ Xb, const int* __restrict__ rowptr2,
    const int2* __restrict__ pairs,
    unsigned short* __restrict__ accb, int bin0, int nbins_chunk) {
  int wb0 = (blockIdx.x * 4 + (threadIdx.x >> 6)) * 8;
  if (wb0 >= nbins_chunk) return;
  int lane = threadIdx.x & 63;
  int bin = bin0 + wb0;
  int bounds = 0;
  if (lane < 9) bounds = rowptr2[bin + lane];
  int b[9];
#pragma unroll
  for (int j = 0; j < 9; j++) b[j] = __shfl(bounds, j, 64);

  int sub = lane >> 5;           // 0: first bin of pair, 1: second
  int half = lane & 31;

#pragma unroll
  for (int j = 0; j < 4; j++) {
    int pA = sub ? b[2 * j + 1] : b[2 * j];
    int pB = sub ? b[2 * j + 2] : b[2 * j + 1];
    int cnt = pB - pA;
    int idx = (cnt > 0) ? pA : 0;
    int2 rec = pairs[idx];
    float w = __int_as_float(rec.y);
    float a0, a1, a2, a3;
    if (C == 64) {
      unsigned u = *(const unsigned*)(Xb + (long)rec.x * 64 + half * 2);
      a0 = (cnt > 0) ? w * b2f((unsigned short)(u & 0xffffu)) : 0.f;
      a1 = (cnt > 0) ? w * b2f((unsigned short)(u >> 16)) : 0.f;
      a2 = a3 = 0.f;
    } else {
      unsigned long long u = *(const unsigned long long*)(Xb + (long)rec.x * 128 + half * 4);
      a0 = (cnt > 0) ? w * b2f((unsigned short)(u & 0xffffu)) : 0.f;
      a1 = (cnt > 0) ? w * b2f((unsigned short)((u >> 16) & 0xffffu)) : 0.f;
      a2 = (cnt > 0) ? w * b2f((unsigned short)((u >> 32) & 0xffffu)) : 0.f;
      a3 = (cnt > 0) ? w * b2f((unsigned short)(u >> 48)) : 0.f;
    }
    // rare extras (divergent, ~0.25/bin)
    for (int p = pA + 1; p < pB; p++) {
      int2 r = pairs[p];
      float w2 = __int_as_float(r.y);
      if (C == 64) {
        unsigned u = *(const unsigned*)(Xb + (long)r.x * 64 + half * 2);
        a0 += w2 * b2f((unsigned short)(u & 0xffffu));
        a1 += w2 * b2f((unsigned short)(u >> 16));
      } else {
        unsigned long long u = *(const unsigned long long*)(Xb + (long)r.x * 128 + half * 4);
        a0 += w2 * b2f((unsigned short)(u & 0xffffu));
        a1 += w2 * b2f((unsigned short)((u >> 16) & 0xffffu));
        a2 += w2 * b2f((unsigned short)((u >> 32) & 0xffffu));
        a3 += w2 * b2f((unsigned short)(u >> 48));
      }
    }
    int wb = wb0 + 2 * j + sub;
    if (wb < nbins_chunk) {
      if (C == 64) {
        unsigned pk = (unsigned)f2b(a0) | ((unsigned)f2b(a1) << 16);
        *(unsigned*)(accb + (long)wb * 64 + half * 2) = pk;
      } else {
        unsigned long long pk = (unsigned long long)((unsigned)f2b(a0) | ((unsigned)f2b(a1) << 16))
                              | ((unsigned long long)((unsigned)f2b(a2) | ((unsigned)f2b(a3) << 16)) << 32);
        *(unsigned long long*)(accb + (long)wb * 128 + half * 4) = pk;
      }
    }
  }
}

// ---------------- LDS-staged MFMA GEMM, 128 cols, K-extension for root GEMM ------
template<int NCOLS, int EC, bool ATOMIC>
__global__ __launch_bounds__(256, 2) void gemm_tile(
    const unsigned short* __restrict__ A, const unsigned short* __restrict__ Aext,
    const unsigned short* __restrict__ Bt, const unsigned short* __restrict__ Bext,
    float* __restrict__ C, int M, int KSP) {
  __shared__ unsigned short As[128 * 32];
  __shared__ unsigned short Bs[128 * 32];
  int wid = threadIdx.x >> 6, lane = threadIdx.x & 63;
  int row0 = blockIdx.x * 128;
  int Ktot = KSP + EC;
  int nslice = gridDim.y;
  int kslice = CDIV(Ktot / 32, nslice) * 32;
  int kbeg = blockIdx.y * kslice;
  int kend = kbeg + kslice; if (kend > Ktot) kend = Ktot;
  if (kbeg >= Ktot) return;

  int sub = lane & 3;
  int rload = lane >> 2;
  int q = lane >> 4, m16 = lane & 15;

  floatx4 acc[2][8];
#pragma unroll
  for (int t = 0; t < 2; t++)
#pragma unroll
    for (int c = 0; c < 8; c++) acc[t][c] = (floatx4){0.f, 0.f, 0.f, 0.f};

  for (int k0 = kbeg; k0 < kend; k0 += 32) {
    __syncthreads();
#pragma unroll
    for (int j = 0; j < 2; j++) {
      int tr = (wid * 2 + j) * 16 + rload;
      int gr = row0 + tr; if (gr >= M) gr = M - 1;
      const unsigned short* ap;
      const unsigned short* bp;
      if (k0 < KSP) {
        ap = A + (long)gr * KSP + k0 + sub * 8;
        bp = Bt + (long)tr * KSP + k0 + sub * 8;
      } else {
        ap = Aext + (long)gr * EC + (k0 - KSP) + sub * 8;
        bp = Bext + (long)tr * EC + (k0 - KSP) + sub * 8;
      }
      ld_g2l16(ap, As + (wid * 2 + j) * 512);
      ld_g2l16(bp, Bs + (wid * 2 + j) * 512);
    }
    __syncthreads();
#pragma unroll
    for (int t = 0; t < 2; t++) {
      int arow = wid * 32 + t * 16 + m16;
      short8 a = *(const short8*)(As + arow * 32 + q * 8);
#pragma unroll
      for (int c = 0; c < 8; c++) {
        short8 b = *(const short8*)(Bs + (c * 16 + m16) * 32 + q * 8);
        acc[t][c] = __builtin_amdgcn_mfma_f32_16x16x32_bf16(a, b, acc[t][c], 0, 0, 0);
      }
    }
  }

#pragma unroll
  for (int t = 0; t < 2; t++) {
#pragma unroll
    for (int c = 0; c < 8; c++) {
#pragma unroll
      for (int r = 0; r < 4; r++) {
        int orow = row0 + wid * 32 + t * 16 + q * 4 + r;
        if (orow < M) {
          float* p = &C[(long)orow * NCOLS + c * 16 + m16];
          if (ATOMIC) atomicAdd(p, acc[t][c][r]);
          else *p = acc[t][c][r];
        }
      }
    }
  }
}

// ---------------- 128x256 tile GEMM with K-extension (conv1+shortcut+roots) ------
template<int EC, bool ATOMIC>
__global__ __launch_bounds__(256, 2) void gemm_tile_w256(
    const unsigned short* __restrict__ A, const unsigned short* __restrict__ Aext,
    const unsigned short* __restrict__ Bt, const unsigned short* __restrict__ Bext,
    float* __restrict__ C, int M, int KSP) {
  __shared__ unsigned short As[128 * 32];
  __shared__ unsigned short Bs[256 * 32];
  int wid = threadIdx.x >> 6, lane = threadIdx.x & 63;
  int row0 = blockIdx.x * 128;
  int Ktot = KSP + EC;
  int nslice = gridDim.y;
  int kslice = CDIV(Ktot / 32, nslice) * 32;
  int kbeg = blockIdx.y * kslice;
  int kend = kbeg + kslice; if (kend > Ktot) kend = Ktot;
  if (kbeg >= Ktot) return;

  int sub = lane & 3;
  int rload = lane >> 2;
  int q = lane >> 4, m16 = lane & 15;

  floatx4 acc[2][16];
#pragma unroll
  for (int t = 0; t < 2; t++)
#pragma unroll
    for (int c = 0; c < 16; c++) acc[t][c] = (floatx4){0.f, 0.f, 0.f, 0.f};

  for (int k0 = kbeg; k0 < kend; k0 += 32) {
    __syncthreads();
    bool sp = (k0 < KSP);
    int ke = sp ? k0 : (k0 - KSP);
#pragma unroll
    for (int j = 0; j < 2; j++) {
      int tr = (wid * 2 + j) * 16 + rload;
      int gr = row0 + tr; if (gr >= M) gr = M - 1;
      const unsigned short* ap = sp ? (A + (long)gr * KSP + ke + sub * 8)
                                    : (Aext + (long)gr * EC + ke + sub * 8);
      ld_g2l16(ap, As + (wid * 2 + j) * 512);
    }
#pragma unroll
    for (int j = 0; j < 4; j++) {
      int tr = (wid * 4 + j) * 16 + rload;
      const unsigned short* bp = sp ? (Bt + (long)tr * KSP + ke + sub * 8)
                                    : (Bext + (long)tr * EC + ke + sub * 8);
      ld_g2l16(bp, Bs + (wid * 4 + j) * 512);
    }
    __syncthreads();
#pragma unroll
    for (int t = 0; t < 2; t++) {
      int arow = wid * 32 + t * 16 + m16;
      short8 a = *(const short8*)(As + arow * 32 + q * 8);
#pragma unroll
      for (int c = 0; c < 16; c++) {
        short8 b = *(const short8*)(Bs + (c * 16 + m16) * 32 + q * 8);
        acc[t][c] = __builtin_amdgcn_mfma_f32_16x16x32_bf16(a, b, acc[t][c], 0, 0, 0);
      }
    }
  }

#pragma unroll
  for (int t = 0; t < 2; t++) {
#pragma unroll
    for (int c = 0; c < 16; c++) {
#pragma unroll
      for (int r = 0; r < 4; r++) {
        int orow = row0 + wid * 32 + t * 16 + q * 4 + r;
        if (orow < M) {
          float* p = &C[(long)orow * 256 + c * 16 + m16];
          if (ATOMIC) atomicAdd(p, acc[t][c][r]);
          else *p = acc[t][c][r];
        }
      }
    }
  }
}

// ---------------- epilogues (root folded into GEMM; weights carry 1/deg) --------
__global__ void finalize_stats(const float* __restrict__ msgaug,
                               const float* __restrict__ bias,
                               float* __restrict__ out, float* __restrict__ stats, int n) {
  int c = threadIdx.x & 127;
  float bv = bias[c];
  float s = 0.f, s2 = 0.f;
  long tot = (long)n * COUT;
  long stride = (long)gridDim.x * 256;
  for (long i = (long)blockIdx.x * 256 + threadIdx.x; i < tot; i += stride) {
    int r = (int)(i >> 7);
    float v = msgaug[(long)r * 256 + c] + bv;
    out[i] = v;
    s += v; s2 += v * v;
  }
  __shared__ float ls[256], ls2[256];
  ls[threadIdx.x] = s; ls2[threadIdx.x] = s2;
  __syncthreads();
  if (threadIdx.x < 128) {
    atomicAdd(&stats[c], ls[threadIdx.x] + ls[threadIdx.x + 128]);
    atomicAdd(&stats[128 + c], ls2[threadIdx.x] + ls2[threadIdx.x + 128]);
  }
}

__global__ void finalize2_dual(const float* __restrict__ msg2, const float* __restrict__ b2,
                               const float* __restrict__ msgaug, const float* __restrict__ bsc,
                               float* __restrict__ h2r, float* __restrict__ sraw,
                               float* __restrict__ stats2, float* __restrict__ statssc, int n) {
  int c = threadIdx.x & 127;
  float bv2 = b2[c], bvsc = bsc[c];
  float sa = 0.f, sb = 0.f, ta = 0.f, tb = 0.f;
  long tot = (long)n * COUT;
  long stride = (long)gridDim.x * 256;
  for (long i = (long)blockIdx.x * 256 + threadIdx.x; i < tot; i += stride) {
    int r = (int)(i >> 7);
    float v2 = msg2[i] + bv2;
    h2r[i] = v2;
    sa += v2; sb += v2 * v2;
    float vs = msgaug[(long)r * 256 + 128 + c] + bvsc;
    sraw[i] = vs;
    ta += vs; tb += vs * vs;
  }
  __shared__ float l0[256], l1[256], l2[256], l3[256];
  l0[threadIdx.x] = sa; l1[threadIdx.x] = sb; l2[threadIdx.x] = ta; l3[threadIdx.x] = tb;
  __syncthreads();
  if (threadIdx.x < 128) {
    atomicAdd(&stats2[c], l0[threadIdx.x] + l0[threadIdx.x + 128]);
    atomicAdd(&stats2[128 + c], l1[threadIdx.x] + l1[threadIdx.x + 128]);
    atomicAdd(&statssc[c], l2[threadIdx.x] + l2[threadIdx.x + 128]);
    atomicAdd(&statssc[128 + c], l3[threadIdx.x] + l3[threadIdx.x + 128]);
  }
}

__global__ void bn_elu_kernel(float* __restrict__ h, unsigned short* __restrict__ hb,
                              const float* __restrict__ stats, const float* __restrict__ g,
                              const float* __restrict__ be, int n) {
  long i = (long)blockIdx.x * 256 + threadIdx.x;
  if (i >= (long)n * COUT) return;
  int c = (int)(i & 127);
  float inv_n = 1.0f / n;
  float mu = stats[c] * inv_n;
  float var = stats[128 + c] * inv_n - mu * mu;
  float v = (h[i] - mu) * rsqrtf(var + EPS) * g[c] + be[c];
  v = v > 0.f ? v : expm1f(v);
  h[i] = v;
  hb[i] = f2b(v);
}

__global__ void final_out_kernel(const float* __restrict__ h2, const float* __restrict__ sraw,
                                 const float* __restrict__ st2, const float* __restrict__ stsc,
                                 const float* __restrict__ g2, const float* __restrict__ be2,
                                 const float* __restrict__ gsc, const float* __restrict__ besc,
                                 float* __restrict__ out, int n) {
  long i = (long)blockIdx.x * 256 + threadIdx.x;
  if (i >= (long)n * COUT) return;
  int c = (int)(i & 127);
  float inv_n = 1.0f / n;
  float mu2 = st2[c] * inv_n;
  float var2 = st2[128 + c] * inv_n - mu2 * mu2;
  float a = (h2[i] - mu2) * rsqrtf(var2 + EPS) * g2[c] + be2[c];
  float musc = stsc[c] * inv_n;
  float varsc = stsc[128 + c] * inv_n - musc * musc;
  float b = (sraw[i] - musc) * rsqrtf(varsc + EPS) * gsc[c] + besc[c];
  float v = a + b;
  out[i] = v > 0.f ? v : expm1f(v);
}

// ---------------- host ----------------
extern "C" void kernel_launch(void* const* d_in, const int* in_sizes, int n_in,
                              void* d_out, int out_size, void* d_ws, size_t ws_size,
                              hipStream_t stream) {
  const float* x    = (const float*)d_in[0];
  const int*   eidx = (const int*)d_in[1];
  const float* attr = (const float*)d_in[2];
  const float* W1   = (const float*)d_in[3];
  const float* Wr1  = (const float*)d_in[4];
  const float* b1   = (const float*)d_in[5];
  const float* g1   = (const float*)d_in[6];
  const float* be1  = (const float*)d_in[7];
  const float* W2   = (const float*)d_in[8];
  const float* Wr2  = (const float*)d_in[9];
  const float* b2   = (const float*)d_in[10];
  const float* g2   = (const float*)d_in[11];
  const float* be2  = (const float*)d_in[12];
  const float* Wsc  = (const float*)d_in[13];
  const float* Wrsc = (const float*)d_in[14];
  const float* bsc  = (const float*)d_in[15];
  const float* gsc  = (const float*)d_in[16];
  const float* besc = (const float*)d_in[17];
  float* out = (float*)d_out;

  const int* src = eidx;
  const int* dst = eidx + N_EDGES;

  char* base = (char*)d_ws;
  size_t off = 0;
  auto alloc = [&](size_t bytes) -> char* {
    char* p = base + off;
    off += (bytes + 255) & ~(size_t)255;
    return p;
  };
  int* ecnt   = (int*)alloc((size_t)N_NODES * 4);
  int* erowptr= (int*)alloc((size_t)(N_NODES + 1) * 4);
  int* ecur   = (int*)alloc((size_t)N_NODES * 4);
  int* eorder = (int*)alloc((size_t)N_EDGES * 4);
  int* rowptr2= (int*)alloc((size_t)(NBINS + 1) * 4);
  int2* pairs = (int2*)alloc((size_t)NPAIRS * 8);
  unsigned short* xb    = (unsigned short*)alloc((size_t)N_NODES * CIN * 2);
  unsigned short* hb    = (unsigned short*)alloc((size_t)N_NODES * COUT * 2);
  unsigned short* W1aug = (unsigned short*)alloc((size_t)256 * KTOT * CIN * 2);
  unsigned short* W2t   = (unsigned short*)alloc((size_t)COUT * KTOT * COUT * 2);
  unsigned short* rootBt= (unsigned short*)alloc((size_t)256 * CIN * 2);
  unsigned short* Wr2t  = (unsigned short*)alloc((size_t)COUT * COUT * 2);
  float* msgaug= (float*)alloc((size_t)N_NODES * 256 * 4);    // conv1+shortcut (zeroed)
  float* msg2  = (float*)alloc((size_t)N_NODES * COUT * 4);   // conv2 (zeroed, adjacent)
  float* h1    = (float*)alloc((size_t)N_NODES * COUT * 4);
  float* h2r   = (float*)alloc((size_t)N_NODES * COUT * 4);
  float* sraw  = (float*)alloc((size_t)N_NODES * COUT * 4);
  float* stats = (float*)alloc(6 * 128 * 4);
  unsigned short* accb = (unsigned short*)(base + off);
  (void)ws_size;
  const int SPLIT1 = 5;   // conv1: 79*5=395 blocks
  const int SPLIT2 = 10;  // conv2: 28*10=280 blocks per chunk
  const int CH2 = 3520;   // conv2 chunk: 112.6 MB < 256 MB L3

  hipMemsetAsync(ecnt, 0, (size_t)N_NODES * 4, stream);
  hipMemsetAsync(msgaug, 0, (size_t)N_NODES * (256 + 128) * 4, stream); // msgaug + msg2

  // edge CSR: dst-sorted edge permutation
  ecount<<<CDIV(N_EDGES, 256), 256, 0, stream>>>(dst, ecnt, N_EDGES);
  escan<<<1, 256, 0, stream>>>(ecnt, erowptr, ecur, N_NODES, rowptr2, stats);
  efill<<<CDIV(N_EDGES, 256), 256, 0, stream>>>(dst, ecur, eorder, N_EDGES);

  // per-node pair build (weights carry 1/deg)
  build_pairs<<<CDIV(N_NODES, 4), 256, 0, stream>>>(eorder, erowptr, src, attr,
                                                    rowptr2, pairs);

  const long CONV_TOT = 640000L + 1024000L + 2048000L + 8192 + 8192 + 16384 + 1024000L;
  convert_all<<<CDIV(CONV_TOT, 256), 256, 0, stream>>>(x, W1, W2, Wr1, Wrsc, Wr2, Wsc,
                                                       xb, W1aug, W2t, rootBt, Wr2t);

  // ---- conv1 + shortcut spline + both root GEMMs (K-extension) ----
  {
    scatter_bins<64><<<CDIV(NBINS, 32), 256, 0, stream>>>(xb, rowptr2, pairs, accb,
                                                          0, NBINS);
    dim3 g(CDIV(N_NODES, 128), SPLIT1);
    gemm_tile_w256<64, true><<<g, 256, 0, stream>>>(
        accb, xb, W1aug, rootBt, msgaug, N_NODES, KTOT * CIN);
  }
  finalize_stats<<<64, 256, 0, stream>>>(msgaug, b1, h1, stats, N_NODES);
  bn_elu_kernel<<<CDIV(N_NODES * COUT, 256), 256, 0, stream>>>(h1, hb, stats, g1, be1, N_NODES);

  // ---- conv2 + root GEMM (K-extension), chunked so accb chunk stays L3-resident
  for (int c0 = 0; c0 < N_NODES; c0 += CH2) {
    int cm = (N_NODES - c0 < CH2) ? (N_NODES - c0) : CH2;
    int nbc = cm * KTOT;
    scatter_bins<128><<<CDIV(nbc, 32), 256, 0, stream>>>(hb, rowptr2, pairs, accb,
                                                         c0 * KTOT, nbc);
    dim3 g(CDIV(cm, 128), SPLIT2);
    gemm_tile<COUT, 128, true><<<g, 256, 0, stream>>>(
        accb, hb + (size_t)c0 * COUT, W2t, Wr2t,
        msg2 + (size_t)c0 * COUT, cm, KTOT * COUT);
  }
  finalize2_dual<<<64, 256, 0, stream>>>(msg2, b2, msgaug, bsc, h2r, sraw,
                                         stats + 256, stats + 512, N_NODES);

  // ---- output ----
  final_out_kernel<<<CDIV(N_NODES * COUT, 256), 256, 0, stream>>>(
      h2r, sraw, stats + 256, stats + 512, g2, be2, gsc, besc, out, N_NODES);
}